// Round 2
// baseline (202.288 us; speedup 1.0000x reference)
//
#include <hip/hip_runtime.h>

typedef unsigned short u16;
typedef __attribute__((ext_vector_type(8))) short bf16x8;
typedef __attribute__((ext_vector_type(4))) float f32x4;

#define B_SZ 4
#define S_SZ 1024
#define D_SZ 1024
#define H_SZ 16
#define E_SZ 64
#define M_SZ (B_SZ * S_SZ)   // 4096

__device__ __forceinline__ u16 f2bf(float f) {
  union { float f; unsigned u; } x; x.f = f;
  unsigned r = (x.u + 0x7FFFu + ((x.u >> 16) & 1u)) >> 16;
  return (u16)r;
}

__device__ __forceinline__ void async16(const void* g, void* l) {
  __builtin_amdgcn_global_load_lds(
      (const __attribute__((address_space(1))) void*)g,
      (__attribute__((address_space(3))) void*)l, 16, 0, 0);
}

__device__ __forceinline__ f32x4 mfma16(bf16x8 a, bf16x8 b, f32x4 c) {
  return __builtin_amdgcn_mfma_f32_16x16x32_bf16(a, b, c, 0, 0, 0);
}

// ---------------- cast f32 -> bf16, 8 elems/thread ----------------
__global__ void cast_bf16_k(const float* __restrict__ in, u16* __restrict__ out, int n) {
  int i = (blockIdx.x * 256 + threadIdx.x) * 8;
  if (i >= n) return;
  float4 a = *(const float4*)(in + i);
  float4 b = *(const float4*)(in + i + 4);
  alignas(16) u16 r[8];
  r[0] = f2bf(a.x); r[1] = f2bf(a.y); r[2] = f2bf(a.z); r[3] = f2bf(a.w);
  r[4] = f2bf(b.x); r[5] = f2bf(b.y); r[6] = f2bf(b.z); r[7] = f2bf(b.w);
  *(uint4*)(out + i) = *(uint4*)r;
}

// ------------- W [H,D,E] f32 -> WT [H*E, D] bf16 (B^T layout) -------------
// block: one h, 64 d-rows; grid = H*16
__global__ void transW(const float* __restrict__ W, u16* __restrict__ WT) {
  __shared__ float tile[64 * 68];
  const int tid = threadIdx.x;
  const int h = blockIdx.x >> 4;
  const int d0 = (blockIdx.x & 15) << 6;
  // load ALL 64 d-rows x 64 e-cols (4 chunks of 16 rows) -- R1 bug was 1 chunk
#pragma unroll
  for (int c = 0; c < 4; ++c) {
    const int dd = c * 16 + (tid >> 4);
    const int e4 = (tid & 15) << 2;
    float4 vq = *(const float4*)(W + (h << 16) + ((d0 + dd) << 6) + e4);
    *(float4*)(tile + dd * 68 + e4) = vq;
  }
  __syncthreads();
  {
    const int e = tid >> 2;
    const int dc = (tid & 3) << 4;
    alignas(16) u16 outv[16];
#pragma unroll
    for (int i = 0; i < 16; ++i) outv[i] = f2bf(tile[(dc + i) * 68 + e]);
    u16* dst = WT + (((size_t)(h << 6) + e) << 10) + d0 + dc;
    *(uint4*)(dst) = *(uint4*)outv;
    *(uint4*)(dst + 8) = *(uint4*)(outv + 8);
  }
}

// ---------------- GEMM: C[M,N] = A[M,K] * BT[N,K]^T + bias, scaled ----------------
// 128x128 tile, BK=64, 4 waves (2x2 of 64x64), 16x16x32 bf16 MFMA.
// LDS linear dest via global_load_lds; swizzle applied on global source (T2 / rule 21).
template <int OUT_BF16>
__global__ __launch_bounds__(256)
void gemm_bt(const u16* __restrict__ A, const u16* __restrict__ BT,
             const float* __restrict__ bias, void* __restrict__ Cout,
             int M, int N, int K, float scale) {
  __shared__ u16 Al[128 * 64];
  __shared__ u16 Bl[128 * 64];
  const int tid = threadIdx.x;
  const int wave = tid >> 6;
  const int lane = tid & 63;
  const int l15 = lane & 15, lq = lane >> 4;
  const int nbn = N >> 7;
  const int bm = blockIdx.x / nbn;
  const int bn = blockIdx.x - bm * nbn;
  const int row0 = bm << 7, col0 = bn << 7;
  const int wr = ((wave >> 1) & 1) << 6;
  const int wc = (wave & 1) << 6;

  f32x4 acc[4][4];
#pragma unroll
  for (int m = 0; m < 4; ++m)
#pragma unroll
    for (int n = 0; n < 4; ++n) acc[m][n] = (f32x4)0.0f;

  for (int k0 = 0; k0 < K; k0 += 64) {
    __syncthreads();
#pragma unroll
    for (int c = 0; c < 4; ++c) {
      const int x = c * 4096 + tid * 16;           // linear LDS byte
      const int g = x ^ (((x >> 7) & 7) << 4);     // pre-swizzled source byte
      const int row = g >> 7;
      const int cb = g & 127;
      const u16* ga = A + (size_t)(row0 + row) * K + k0 + (cb >> 1);
      const u16* gb = BT + (size_t)(col0 + row) * K + k0 + (cb >> 1);
      async16(ga, (char*)Al + c * 4096 + (wave << 10));
      async16(gb, (char*)Bl + c * 4096 + (wave << 10));
    }
    __syncthreads();

    bf16x8 af[4][2], bfr[4][2];
#pragma unroll
    for (int m = 0; m < 4; ++m)
#pragma unroll
      for (int kf = 0; kf < 2; ++kf) {
        int r = wr + m * 16 + l15;
        int byte = ((r << 7) + kf * 64 + lq * 16) ^ ((r & 7) << 4);
        af[m][kf] = *(const bf16x8*)((const char*)Al + byte);
      }
#pragma unroll
    for (int n = 0; n < 4; ++n)
#pragma unroll
      for (int kf = 0; kf < 2; ++kf) {
        int r = wc + n * 16 + l15;
        int byte = ((r << 7) + kf * 64 + lq * 16) ^ ((r & 7) << 4);
        bfr[n][kf] = *(const bf16x8*)((const char*)Bl + byte);
      }
#pragma unroll
    for (int kf = 0; kf < 2; ++kf)
#pragma unroll
      for (int m = 0; m < 4; ++m)
#pragma unroll
        for (int n = 0; n < 4; ++n)
          acc[m][n] = mfma16(af[m][kf], bfr[n][kf], acc[m][n]);
  }

#pragma unroll
  for (int m = 0; m < 4; ++m)
#pragma unroll
    for (int n = 0; n < 4; ++n) {
      int col = col0 + wc + n * 16 + l15;
      float bv = bias[col];
#pragma unroll
      for (int j = 0; j < 4; ++j) {
        int row = row0 + wr + m * 16 + lq * 4 + j;
        float val = (acc[m][n][j] + bv) * scale;
        if (OUT_BF16)
          ((u16*)Cout)[(size_t)row * N + col] = f2bf(val);
        else
          ((float*)Cout)[(size_t)row * N + col] = val;
      }
    }
}

// ---------------- flash attention ----------------
// grid: B*H*(S/64) blocks; 4 waves, each wave owns 16 q-rows.
// Q,K,V layout [B,S,H,E] bf16 (= proj GEMM output [B*S, 1024]).
// Scale 1/sqrt(E) already folded into Q.
__global__ __launch_bounds__(256)
void attn(const u16* __restrict__ Qp, const u16* __restrict__ Kp,
          const u16* __restrict__ Vp, u16* __restrict__ Ow) {
  __shared__ u16 Kl[64 * 64];    // [t][e], swizzled
  __shared__ u16 VTl[64 * 64];   // [e][t], swizzled
  __shared__ float Pl[4 * 16 * 64];  // per-wave P staging, swizzled
  const int tid = threadIdx.x;
  const int wave = tid >> 6;
  const int lane = tid & 63;
  const int l15 = lane & 15, lq = lane >> 4;
  const int qt = blockIdx.x & 15;
  const int bh = blockIdx.x >> 4;
  const int b = bh >> 4, h = bh & 15;
  const size_t bS = (size_t)b * S_SZ;

  bf16x8 aq[2];
  {
    const u16* qptr = Qp + ((bS + qt * 64 + wave * 16 + l15) << 10) + h * 64 + lq * 8;
    aq[0] = *(const bf16x8*)(qptr);
    aq[1] = *(const bf16x8*)(qptr + 32);
  }

  f32x4 o[4];
#pragma unroll
  for (int n = 0; n < 4; ++n) o[n] = (f32x4)0.0f;
  float m_run[4] = {-1e30f, -1e30f, -1e30f, -1e30f};
  float l_run[4] = {0.f, 0.f, 0.f, 0.f};
  float* Pw = Pl + wave * 1024;

  for (int t0 = 0; t0 < S_SZ; t0 += 64) {
    __syncthreads();
    // stage K tile (swizzled source, linear LDS dest)
#pragma unroll
    for (int c = 0; c < 2; ++c) {
      const int x = c * 4096 + tid * 16;
      const int g = x ^ (((x >> 7) & 7) << 4);
      const int trow = g >> 7;
      const int cb = g & 127;
      const u16* ga = Kp + ((bS + t0 + trow) << 10) + h * 64 + (cb >> 1);
      async16(ga, (char*)Kl + c * 4096 + (wave << 10));
    }
    // stage V^T via registers (coalesced read, transposed swizzled write)
    {
      const int r = tid >> 2;
      const int ch = tid & 3;
      const u16* gv = Vp + ((bS + t0 + r) << 10) + h * 64 + ch * 16;
      alignas(16) u16 vv[16];
      *(uint4*)(vv) = *(const uint4*)(gv);
      *(uint4*)(vv + 8) = *(const uint4*)(gv + 8);
#pragma unroll
      for (int i = 0; i < 16; ++i) {
        int e = ch * 16 + i;
        int byte = ((e << 7) + (r << 1)) ^ ((e & 7) << 4);
        *(u16*)((char*)VTl + byte) = vv[i];
      }
    }
    __syncthreads();

    // QK^T : s[n] covers score cols n*16..n*16+15
    f32x4 s[4];
#pragma unroll
    for (int n = 0; n < 4; ++n) s[n] = (f32x4)0.0f;
#pragma unroll
    for (int n = 0; n < 4; ++n)
#pragma unroll
      for (int kf = 0; kf < 2; ++kf) {
        int r = n * 16 + l15;
        int byte = ((r << 7) + kf * 64 + lq * 16) ^ ((r & 7) << 4);
        bf16x8 bk = *(const bf16x8*)((const char*)Kl + byte);
        s[n] = mfma16(aq[kf], bk, s[n]);
      }

    // online softmax (rows lq*4+j; reduce across the 16 lanes of the row group)
    float mx[4], alpha[4], rs[4];
#pragma unroll
    for (int j = 0; j < 4; ++j)
      mx[j] = fmaxf(fmaxf(s[0][j], s[1][j]), fmaxf(s[2][j], s[3][j]));
#pragma unroll
    for (int off = 1; off < 16; off <<= 1)
#pragma unroll
      for (int j = 0; j < 4; ++j)
        mx[j] = fmaxf(mx[j], __shfl_xor(mx[j], off, 64));
#pragma unroll
    for (int j = 0; j < 4; ++j) {
      float mn = fmaxf(m_run[j], mx[j]);
      alpha[j] = __expf(m_run[j] - mn);
      m_run[j] = mn;
      rs[j] = 0.f;
    }
#pragma unroll
    for (int n = 0; n < 4; ++n)
#pragma unroll
      for (int j = 0; j < 4; ++j) {
        float p = __expf(s[n][j] - m_run[j]);
        s[n][j] = p;
        rs[j] += p;
      }
#pragma unroll
    for (int off = 1; off < 16; off <<= 1)
#pragma unroll
      for (int j = 0; j < 4; ++j)
        rs[j] += __shfl_xor(rs[j], off, 64);
#pragma unroll
    for (int j = 0; j < 4; ++j) l_run[j] = l_run[j] * alpha[j] + rs[j];
#pragma unroll
    for (int n = 0; n < 4; ++n)
#pragma unroll
      for (int j = 0; j < 4; ++j) o[n][j] *= alpha[j];

    // P (C-layout) -> LDS f32 (swizzled), same-wave only: no barrier needed
#pragma unroll
    for (int n = 0; n < 4; ++n)
#pragma unroll
      for (int j = 0; j < 4; ++j) {
        int row = lq * 4 + j;
        int byte = ((row << 8) + ((n * 16 + l15) << 2)) ^ ((row & 7) << 5);
        *(float*)((char*)Pw + byte) = s[n][j];
      }

    // PV: A = P (A-layout read back), B = V^T rows
#pragma unroll
    for (int kf = 0; kf < 2; ++kf) {
      int base = ((l15 << 8) + ((kf * 32 + lq * 8) << 2)) ^ ((l15 & 7) << 5);
      f32x4 plo = *(const f32x4*)((const char*)Pw + base);
      f32x4 phi = *(const f32x4*)((const char*)Pw + base + 16);
      bf16x8 pa;
#pragma unroll
      for (int i = 0; i < 4; ++i) {
        pa[i] = (short)f2bf(plo[i]);
        pa[i + 4] = (short)f2bf(phi[i]);
      }
#pragma unroll
      for (int n = 0; n < 4; ++n) {
        int vr = n * 16 + l15;
        int byte = ((vr << 7) + kf * 64 + lq * 16) ^ ((vr & 7) << 4);
        bf16x8 bv = *(const bf16x8*)((const char*)VTl + byte);
        o[n] = mfma16(pa, bv, o[n]);
      }
    }
  }

#pragma unroll
  for (int n = 0; n < 4; ++n)
#pragma unroll
    for (int j = 0; j < 4; ++j) {
      float val = o[n][j] / l_run[j];
      int row = qt * 64 + wave * 16 + lq * 4 + j;
      int col = h * 64 + n * 16 + l15;
      Ow[((bS + row) << 10) + col] = f2bf(val);
    }
}

extern "C" void kernel_launch(void* const* d_in, const int* in_sizes, int n_in,
                              void* d_out, int out_size, void* d_ws, size_t ws_size,
                              hipStream_t stream) {
  const float* q  = (const float*)d_in[0];
  const float* k  = (const float*)d_in[1];
  const float* v  = (const float*)d_in[2];
  const float* Wq = (const float*)d_in[3];
  const float* bq = (const float*)d_in[4];
  const float* Wk = (const float*)d_in[5];
  const float* bk = (const float*)d_in[6];
  const float* Wv = (const float*)d_in[7];
  const float* bv = (const float*)d_in[8];
  const float* Wo = (const float*)d_in[9];
  const float* bo = (const float*)d_in[10];

  char* w = (char*)d_ws;
  const size_t MB = 1u << 20;
  u16* qb  = (u16*)(w + 0 * MB);
  u16* kb  = (u16*)(w + 8 * MB);
  u16* vb  = (u16*)(w + 16 * MB);
  u16* WqT = (u16*)(w + 24 * MB);
  u16* WkT = (u16*)(w + 26 * MB);
  u16* WvT = (u16*)(w + 28 * MB);
  u16* Wob = (u16*)(w + 30 * MB);
  u16* Qp  = (u16*)(w + 32 * MB);
  u16* Kp  = (u16*)(w + 40 * MB);
  u16* Vp  = (u16*)(w + 48 * MB);
  u16* wvb = (u16*)(w + 56 * MB);

  const int nBSD = B_SZ * S_SZ * D_SZ;   // 4M
  const int nW = H_SZ * D_SZ * E_SZ;     // 1M

  cast_bf16_k<<<nBSD / 2048, 256, 0, stream>>>(q, qb, nBSD);
  cast_bf16_k<<<nBSD / 2048, 256, 0, stream>>>(k, kb, nBSD);
  cast_bf16_k<<<nBSD / 2048, 256, 0, stream>>>(v, vb, nBSD);
  cast_bf16_k<<<nW / 2048, 256, 0, stream>>>(Wo, Wob, nW);
  transW<<<H_SZ * 16, 256, 0, stream>>>(Wq, WqT);
  transW<<<H_SZ * 16, 256, 0, stream>>>(Wk, WkT);
  transW<<<H_SZ * 16, 256, 0, stream>>>(Wv, WvT);

  // projections: scale folded into Q (1/sqrt(E) = 0.125)
  gemm_bt<1><<<(M_SZ / 128) * (D_SZ / 128), 256, 0, stream>>>(qb, WqT, bq, Qp, M_SZ, D_SZ, D_SZ, 0.125f);
  gemm_bt<1><<<(M_SZ / 128) * (D_SZ / 128), 256, 0, stream>>>(kb, WkT, bk, Kp, M_SZ, D_SZ, D_SZ, 1.0f);
  gemm_bt<1><<<(M_SZ / 128) * (D_SZ / 128), 256, 0, stream>>>(vb, WvT, bv, Vp, M_SZ, D_SZ, D_SZ, 1.0f);

  attn<<<B_SZ * H_SZ * (S_SZ / 64), 256, 0, stream>>>(Qp, Kp, Vp, wvb);

  // out = wv @ Wo^T + bo  (BT = Wo directly), f32 output
  gemm_bt<0><<<(M_SZ / 128) * (D_SZ / 128), 256, 0, stream>>>(wvb, Wob, bo, (float*)d_out, M_SZ, D_SZ, D_SZ, 1.0f);
}

// Round 3
// 150.474 us; speedup vs baseline: 1.3443x; 1.3443x over previous
//
#include <hip/hip_runtime.h>

typedef unsigned short u16;
typedef __attribute__((ext_vector_type(8))) short bf16x8;
typedef __attribute__((ext_vector_type(4))) float f32x4;

#define B_SZ 4
#define S_SZ 1024
#define D_SZ 1024
#define H_SZ 16
#define E_SZ 64
#define M_SZ (B_SZ * S_SZ)   // 4096

__device__ __forceinline__ u16 f2bf(float f) {
  union { float f; unsigned u; } x; x.f = f;
  unsigned r = (x.u + 0x7FFFu + ((x.u >> 16) & 1u)) >> 16;
  return (u16)r;
}

__device__ __forceinline__ void async16(const void* g, void* l) {
  __builtin_amdgcn_global_load_lds(
      (const __attribute__((address_space(1))) void*)g,
      (__attribute__((address_space(3))) void*)l, 16, 0, 0);
}

__device__ __forceinline__ f32x4 mfma16(bf16x8 a, bf16x8 b, f32x4 c) {
  return __builtin_amdgcn_mfma_f32_16x16x32_bf16(a, b, c, 0, 0, 0);
}

// ---------------- fused cast f32 -> bf16 for q,k,v ----------------
__global__ void cast3(const float* __restrict__ q, const float* __restrict__ k,
                      const float* __restrict__ v, u16* __restrict__ oq,
                      u16* __restrict__ ok, u16* __restrict__ ov) {
  int gid = blockIdx.x * 256 + threadIdx.x;       // 3 * 2^19 threads
  int sel = gid >> 19;
  int i = (gid & ((1 << 19) - 1)) << 3;
  const float* in = sel == 0 ? q : (sel == 1 ? k : v);
  u16* out = sel == 0 ? oq : (sel == 1 ? ok : ov);
  float4 a = *(const float4*)(in + i);
  float4 b = *(const float4*)(in + i + 4);
  alignas(16) u16 r[8];
  r[0] = f2bf(a.x); r[1] = f2bf(a.y); r[2] = f2bf(a.z); r[3] = f2bf(a.w);
  r[4] = f2bf(b.x); r[5] = f2bf(b.y); r[6] = f2bf(b.z); r[7] = f2bf(b.w);
  *(uint4*)(out + i) = *(uint4*)r;
}

__global__ void cast_bf16_k(const float* __restrict__ in, u16* __restrict__ out, int n) {
  int i = (blockIdx.x * 256 + threadIdx.x) * 8;
  if (i >= n) return;
  float4 a = *(const float4*)(in + i);
  float4 b = *(const float4*)(in + i + 4);
  alignas(16) u16 r[8];
  r[0] = f2bf(a.x); r[1] = f2bf(a.y); r[2] = f2bf(a.z); r[3] = f2bf(a.w);
  r[4] = f2bf(b.x); r[5] = f2bf(b.y); r[6] = f2bf(b.z); r[7] = f2bf(b.w);
  *(uint4*)(out + i) = *(uint4*)r;
}

// ------------- fused W [H,D,E] f32 -> WT [H*E, D] bf16 for Wq,Wk,Wv -------------
__global__ void transW3(const float* __restrict__ Wq, const float* __restrict__ Wk,
                        const float* __restrict__ Wv, u16* __restrict__ Tq,
                        u16* __restrict__ Tk, u16* __restrict__ Tv) {
  __shared__ float tile[64 * 68];
  const int wsel = blockIdx.x >> 8;
  const int bi = blockIdx.x & 255;
  const float* W = wsel == 0 ? Wq : (wsel == 1 ? Wk : Wv);
  u16* WT = wsel == 0 ? Tq : (wsel == 1 ? Tk : Tv);
  const int tid = threadIdx.x;
  const int h = bi >> 4;
  const int d0 = (bi & 15) << 6;
#pragma unroll
  for (int c = 0; c < 4; ++c) {
    const int dd = c * 16 + (tid >> 4);
    const int e4 = (tid & 15) << 2;
    float4 vq = *(const float4*)(W + (h << 16) + ((d0 + dd) << 6) + e4);
    *(float4*)(tile + dd * 68 + e4) = vq;
  }
  __syncthreads();
  {
    const int e = tid >> 2;
    const int dc = (tid & 3) << 4;
    alignas(16) u16 outv[16];
#pragma unroll
    for (int i = 0; i < 16; ++i) outv[i] = f2bf(tile[(dc + i) * 68 + e]);
    u16* dst = WT + (((size_t)(h << 6) + e) << 10) + d0 + dc;
    *(uint4*)(dst) = *(uint4*)outv;
    *(uint4*)(dst + 8) = *(uint4*)(outv + 8);
  }
}

// ---------------- GEMM core: C = A[4096,1024] * BT[1024,1024]^T + bias ----------------
// m97 structure: 128x128 tile, BK=64, 4 waves, global_load_lds w/ source preswizzle.
// mode 0: f32 row-major; 1: bf16 row-major; 2: bf16 transposed [col][row] (for VpT)
__device__ __forceinline__ void gemm_core(const u16* __restrict__ A,
                                          const u16* __restrict__ BT,
                                          const float* __restrict__ bias,
                                          void* __restrict__ Cout,
                                          float scale, int mode, int bi) {
  __shared__ u16 Al[128 * 64];
  __shared__ u16 Bl[128 * 64];
  const int tid = threadIdx.x;
  const int wave = tid >> 6;
  const int lane = tid & 63;
  const int l15 = lane & 15, lq = lane >> 4;
  const int bm = bi >> 3;
  const int bn = bi & 7;
  const int row0 = bm << 7, col0 = bn << 7;
  const int wr = ((wave >> 1) & 1) << 6;
  const int wc = (wave & 1) << 6;

  f32x4 acc[4][4];
#pragma unroll
  for (int m = 0; m < 4; ++m)
#pragma unroll
    for (int n = 0; n < 4; ++n) acc[m][n] = (f32x4)0.0f;

  for (int k0 = 0; k0 < 1024; k0 += 64) {
    __syncthreads();
#pragma unroll
    for (int c = 0; c < 4; ++c) {
      const int x = c * 4096 + tid * 16;
      const int g = x ^ (((x >> 7) & 7) << 4);
      const int row = g >> 7;
      const int cb = g & 127;
      const u16* ga = A + (size_t)(row0 + row) * 1024 + k0 + (cb >> 1);
      const u16* gb = BT + (size_t)(col0 + row) * 1024 + k0 + (cb >> 1);
      async16(ga, (char*)Al + c * 4096 + (wave << 10));
      async16(gb, (char*)Bl + c * 4096 + (wave << 10));
    }
    __syncthreads();

    bf16x8 af[4][2], bfr[4][2];
#pragma unroll
    for (int m = 0; m < 4; ++m)
#pragma unroll
      for (int kf = 0; kf < 2; ++kf) {
        int r = wr + m * 16 + l15;
        int byte = ((r << 7) + kf * 64 + lq * 16) ^ ((r & 7) << 4);
        af[m][kf] = *(const bf16x8*)((const char*)Al + byte);
      }
#pragma unroll
    for (int n = 0; n < 4; ++n)
#pragma unroll
      for (int kf = 0; kf < 2; ++kf) {
        int r = wc + n * 16 + l15;
        int byte = ((r << 7) + kf * 64 + lq * 16) ^ ((r & 7) << 4);
        bfr[n][kf] = *(const bf16x8*)((const char*)Bl + byte);
      }
#pragma unroll
    for (int kf = 0; kf < 2; ++kf)
#pragma unroll
      for (int m = 0; m < 4; ++m)
#pragma unroll
        for (int n = 0; n < 4; ++n)
          acc[m][n] = mfma16(af[m][kf], bfr[n][kf], acc[m][n]);
  }

#pragma unroll
  for (int m = 0; m < 4; ++m)
#pragma unroll
    for (int n = 0; n < 4; ++n) {
      int col = col0 + wc + n * 16 + l15;
      float bv = bias[col];
      int rowb = row0 + wr + m * 16 + lq * 4;
      if (mode == 2) {
        alignas(8) u16 r4[4];
#pragma unroll
        for (int j = 0; j < 4; ++j) r4[j] = f2bf((acc[m][n][j] + bv) * scale);
        *(uint2*)((u16*)Cout + (size_t)col * 4096 + rowb) = *(uint2*)r4;
      } else if (mode == 1) {
#pragma unroll
        for (int j = 0; j < 4; ++j)
          ((u16*)Cout)[(size_t)(rowb + j) * 1024 + col] = f2bf((acc[m][n][j] + bv) * scale);
      } else {
#pragma unroll
        for (int j = 0; j < 4; ++j)
          ((float*)Cout)[(size_t)(rowb + j) * 1024 + col] = (acc[m][n][j] + bv) * scale;
      }
    }
}

__global__ __launch_bounds__(256)
void gemm3(const u16* __restrict__ qb, const u16* __restrict__ kb, const u16* __restrict__ vb,
           const u16* __restrict__ Tq, const u16* __restrict__ Tk, const u16* __restrict__ Tv,
           const float* __restrict__ bq, const float* __restrict__ bk, const float* __restrict__ bv,
           u16* __restrict__ Qp, u16* __restrict__ Kp, u16* __restrict__ VpT) {
  const int g = blockIdx.x >> 8;
  const int bi = blockIdx.x & 255;
  const u16* A = g == 0 ? qb : (g == 1 ? kb : vb);
  const u16* BT = g == 0 ? Tq : (g == 1 ? Tk : Tv);
  const float* bias = g == 0 ? bq : (g == 1 ? bk : bv);
  void* out = g == 0 ? (void*)Qp : (g == 1 ? (void*)Kp : (void*)VpT);
  gemm_core(A, BT, bias, out, g == 0 ? 0.125f : 1.0f, g == 2 ? 2 : 1, bi);
}

__global__ __launch_bounds__(256)
void gemmO(const u16* __restrict__ A, const u16* __restrict__ BT,
           const float* __restrict__ bias, float* __restrict__ out) {
  gemm_core(A, BT, bias, out, 1.0f, 0, blockIdx.x);
}

// ---------------- flash attention v2 ----------------
// grid B*H*(S/64); 4 waves x 16 q-rows. K [B,S,H,E]; V pre-transposed VpT [H*E][B*S].
// Double-buffered async16 staging for K and V^T; 1 barrier/iter; P staged as bf16.
__global__ __launch_bounds__(256)
void attn(const u16* __restrict__ Qp, const u16* __restrict__ Kp,
          const u16* __restrict__ VpT, u16* __restrict__ Ow) {
  __shared__ alignas(16) u16 Kl[2][64 * 64];
  __shared__ alignas(16) u16 VTl[2][64 * 64];
  __shared__ alignas(16) u16 Pl[4][16 * 64];
  const int tid = threadIdx.x;
  const int wave = tid >> 6;
  const int lane = tid & 63;
  const int l15 = lane & 15, lq = lane >> 4;
  const int qt = blockIdx.x & 15;
  const int bh = blockIdx.x >> 4;
  const int b = bh >> 4, h = bh & 15;
  const size_t bS = (size_t)b * S_SZ;

  // staging source addresses (source-preswizzled; row bits unaffected by XOR)
  const int xs0 = tid * 16, xs1 = 4096 + tid * 16;
  const int r0 = xs0 >> 7, r1 = xs1 >> 7;
  const int c0 = ((xs0 & 127) ^ (((xs0 >> 7) & 7) << 4)) >> 1;
  const int c1 = ((xs1 & 127) ^ (((xs1 >> 7) & 7) << 4)) >> 1;
  const u16* Kb0 = Kp + ((bS + r0) << 10) + h * 64 + c0;
  const u16* Kb1 = Kp + ((bS + r1) << 10) + h * 64 + c1;
  const u16* Vb0 = VpT + (size_t)(h * 64 + r0) * 4096 + bS + c0;
  const u16* Vb1 = VpT + (size_t)(h * 64 + r1) * 4096 + bS + c1;

  bf16x8 aq[2];
  {
    const u16* qptr = Qp + ((bS + qt * 64 + wave * 16 + l15) << 10) + h * 64 + lq * 8;
    aq[0] = *(const bf16x8*)(qptr);
    aq[1] = *(const bf16x8*)(qptr + 32);
  }

  f32x4 o[4];
#pragma unroll
  for (int n = 0; n < 4; ++n) o[n] = (f32x4)0.0f;
  float m_run[4] = {-1e30f, -1e30f, -1e30f, -1e30f};
  float l_run[4] = {0.f, 0.f, 0.f, 0.f};
  u16* Pw = Pl[wave];

  // prologue: stage tile 0
  async16(Kb0, (char*)Kl[0] + xs0);
  async16(Kb1, (char*)Kl[0] + xs1);
  async16(Vb0, (char*)VTl[0] + xs0);
  async16(Vb1, (char*)VTl[0] + xs1);
  __syncthreads();

  int buf = 0;
  for (int t0 = 0; t0 < S_SZ; t0 += 64) {
    // prefetch next tile into other buffer (drained by end-of-iter barrier)
    if (t0 + 64 < S_SZ) {
      const int tn = t0 + 64;
      async16(Kb0 + ((size_t)tn << 10), (char*)Kl[buf ^ 1] + xs0);
      async16(Kb1 + ((size_t)tn << 10), (char*)Kl[buf ^ 1] + xs1);
      async16(Vb0 + tn, (char*)VTl[buf ^ 1] + xs0);
      async16(Vb1 + tn, (char*)VTl[buf ^ 1] + xs1);
    }

    // QK^T
    f32x4 s[4];
#pragma unroll
    for (int n = 0; n < 4; ++n) s[n] = (f32x4)0.0f;
#pragma unroll
    for (int n = 0; n < 4; ++n)
#pragma unroll
      for (int kf = 0; kf < 2; ++kf) {
        int r = n * 16 + l15;
        int byte = ((r << 7) + kf * 64 + lq * 16) ^ ((r & 7) << 4);
        bf16x8 bk = *(const bf16x8*)((const char*)Kl[buf] + byte);
        s[n] = mfma16(aq[kf], bk, s[n]);
      }

    // online softmax (rows q = lq*4+j; reduce across 16 lanes of row group)
    float mx[4], alpha[4], rs[4];
#pragma unroll
    for (int j = 0; j < 4; ++j)
      mx[j] = fmaxf(fmaxf(s[0][j], s[1][j]), fmaxf(s[2][j], s[3][j]));
#pragma unroll
    for (int off = 1; off < 16; off <<= 1)
#pragma unroll
      for (int j = 0; j < 4; ++j)
        mx[j] = fmaxf(mx[j], __shfl_xor(mx[j], off, 64));
#pragma unroll
    for (int j = 0; j < 4; ++j) {
      float mn = fmaxf(m_run[j], mx[j]);
      alpha[j] = __expf(m_run[j] - mn);
      m_run[j] = mn;
      rs[j] = 0.f;
    }
    // exp, accumulate row-sum, write P (bf16, swizzled) in one pass
#pragma unroll
    for (int n = 0; n < 4; ++n)
#pragma unroll
      for (int j = 0; j < 4; ++j) {
        float p = __expf(s[n][j] - m_run[j]);
        rs[j] += p;
        int row = lq * 4 + j;
        int t = n * 16 + l15;
        int byte = (row << 7) + ((t << 1) ^ ((row & 7) << 4));
        *(u16*)((char*)Pw + byte) = f2bf(p);
      }
#pragma unroll
    for (int off = 1; off < 16; off <<= 1)
#pragma unroll
      for (int j = 0; j < 4; ++j)
        rs[j] += __shfl_xor(rs[j], off, 64);
#pragma unroll
    for (int j = 0; j < 4; ++j) l_run[j] = l_run[j] * alpha[j] + rs[j];
#pragma unroll
    for (int n = 0; n < 4; ++n)
#pragma unroll
      for (int j = 0; j < 4; ++j) o[n][j] *= alpha[j];

    // PV: A = P read back as bf16 fragments, B = V^T rows from LDS
#pragma unroll
    for (int kf = 0; kf < 2; ++kf) {
      int pbyte = (l15 << 7) + ((kf * 64 + lq * 16) ^ ((l15 & 7) << 4));
      bf16x8 pa = *(const bf16x8*)((const char*)Pw + pbyte);
#pragma unroll
      for (int n = 0; n < 4; ++n) {
        int vr = n * 16 + l15;
        int byte = ((vr << 7) + kf * 64 + lq * 16) ^ ((vr & 7) << 4);
        bf16x8 bv = *(const bf16x8*)((const char*)VTl[buf] + byte);
        o[n] = mfma16(pa, bv, o[n]);
      }
    }

    __syncthreads();   // drains this iter's prefetch (vmcnt) + syncs buffers
    buf ^= 1;
  }

#pragma unroll
  for (int n = 0; n < 4; ++n)
#pragma unroll
    for (int j = 0; j < 4; ++j) {
      float val = o[n][j] / l_run[j];
      int row = qt * 64 + wave * 16 + lq * 4 + j;
      int col = h * 64 + n * 16 + l15;
      Ow[((bS + row) << 10) + col] = f2bf(val);
    }
}

extern "C" void kernel_launch(void* const* d_in, const int* in_sizes, int n_in,
                              void* d_out, int out_size, void* d_ws, size_t ws_size,
                              hipStream_t stream) {
  const float* q  = (const float*)d_in[0];
  const float* k  = (const float*)d_in[1];
  const float* v  = (const float*)d_in[2];
  const float* Wq = (const float*)d_in[3];
  const float* bq = (const float*)d_in[4];
  const float* Wk = (const float*)d_in[5];
  const float* bk = (const float*)d_in[6];
  const float* Wv = (const float*)d_in[7];
  const float* bv = (const float*)d_in[8];
  const float* Wo = (const float*)d_in[9];
  const float* bo = (const float*)d_in[10];

  char* w = (char*)d_ws;
  const size_t MB = 1u << 20;
  u16* qb  = (u16*)(w + 0 * MB);
  u16* kb  = (u16*)(w + 8 * MB);
  u16* vb  = (u16*)(w + 16 * MB);
  u16* WqT = (u16*)(w + 24 * MB);
  u16* WkT = (u16*)(w + 26 * MB);
  u16* WvT = (u16*)(w + 28 * MB);
  u16* Wob = (u16*)(w + 30 * MB);
  u16* Qp  = (u16*)(w + 32 * MB);
  u16* Kp  = (u16*)(w + 40 * MB);
  u16* VpT = (u16*)(w + 48 * MB);
  u16* wvb = (u16*)(w + 56 * MB);

  const int nW = H_SZ * D_SZ * E_SZ;     // 1M

  cast3<<<6144, 256, 0, stream>>>(q, k, v, qb, kb, vb);
  cast_bf16_k<<<nW / 2048, 256, 0, stream>>>(Wo, Wob, nW);
  transW3<<<768, 256, 0, stream>>>(Wq, Wk, Wv, WqT, WkT, WvT);

  gemm3<<<768, 256, 0, stream>>>(qb, kb, vb, WqT, WkT, WvT, bq, bk, bv, Qp, Kp, VpT);

  attn<<<B_SZ * H_SZ * (S_SZ / 64), 256, 0, stream>>>(Qp, Kp, VpT, wvb);

  gemmO<<<256, 256, 0, stream>>>(wvb, Wob, bo, (float*)d_out);
}

// Round 5
// 133.951 us; speedup vs baseline: 1.5102x; 1.1234x over previous
//
#include <hip/hip_runtime.h>

typedef unsigned short u16;
typedef unsigned int u32;
typedef __attribute__((ext_vector_type(8))) short bf16x8;
typedef __attribute__((ext_vector_type(4))) float f32x4;

#define B_SZ 4
#define S_SZ 1024
#define D_SZ 1024
#define H_SZ 16
#define E_SZ 64
#define M_SZ (B_SZ * S_SZ)   // 4096

__device__ __forceinline__ u16 f2bf(float f) {
  union { float f; unsigned u; } x; x.f = f;
  unsigned r = (x.u + 0x7FFFu + ((x.u >> 16) & 1u)) >> 16;
  return (u16)r;
}

__device__ __forceinline__ u32 pack_bf16(float lo, float hi) {
  return (u32)f2bf(lo) | ((u32)f2bf(hi) << 16);
}

__device__ __forceinline__ void async16(const void* g, void* l) {
  __builtin_amdgcn_global_load_lds(
      (const __attribute__((address_space(1))) void*)g,
      (__attribute__((address_space(3))) void*)l, 16, 0, 0);
}

__device__ __forceinline__ f32x4 mfma16(bf16x8 a, bf16x8 b, f32x4 c) {
  return __builtin_amdgcn_mfma_f32_16x16x32_bf16(a, b, c, 0, 0, 0);
}

// ---------------- fused cast f32 -> bf16 for q,k,v ----------------
__global__ void cast3(const float* __restrict__ q, const float* __restrict__ k,
                      const float* __restrict__ v, u16* __restrict__ oq,
                      u16* __restrict__ ok, u16* __restrict__ ov) {
  int gid = blockIdx.x * 256 + threadIdx.x;       // 3 * 2^19 threads
  int sel = gid >> 19;
  int i = (gid & ((1 << 19) - 1)) << 3;
  const float* in = sel == 0 ? q : (sel == 1 ? k : v);
  u16* out = sel == 0 ? oq : (sel == 1 ? ok : ov);
  float4 a = *(const float4*)(in + i);
  float4 b = *(const float4*)(in + i + 4);
  alignas(16) u16 r[8];
  r[0] = f2bf(a.x); r[1] = f2bf(a.y); r[2] = f2bf(a.z); r[3] = f2bf(a.w);
  r[4] = f2bf(b.x); r[5] = f2bf(b.y); r[6] = f2bf(b.z); r[7] = f2bf(b.w);
  *(uint4*)(out + i) = *(uint4*)r;
}

__global__ void cast_bf16_k(const float* __restrict__ in, u16* __restrict__ out, int n) {
  int i = (blockIdx.x * 256 + threadIdx.x) * 8;
  if (i >= n) return;
  float4 a = *(const float4*)(in + i);
  float4 b = *(const float4*)(in + i + 4);
  alignas(16) u16 r[8];
  r[0] = f2bf(a.x); r[1] = f2bf(a.y); r[2] = f2bf(a.z); r[3] = f2bf(a.w);
  r[4] = f2bf(b.x); r[5] = f2bf(b.y); r[6] = f2bf(b.z); r[7] = f2bf(b.w);
  *(uint4*)(out + i) = *(uint4*)r;
}

// ------------- fused W [H,D,E] f32 -> WT [H*E, D] bf16 for Wq,Wk,Wv -------------
__global__ void transW3(const float* __restrict__ Wq, const float* __restrict__ Wk,
                        const float* __restrict__ Wv, u16* __restrict__ Tq,
                        u16* __restrict__ Tk, u16* __restrict__ Tv) {
  __shared__ float tile[64 * 68];
  const int wsel = blockIdx.x >> 8;
  const int bi = blockIdx.x & 255;
  const float* W = wsel == 0 ? Wq : (wsel == 1 ? Wk : Wv);
  u16* WT = wsel == 0 ? Tq : (wsel == 1 ? Tk : Tv);
  const int tid = threadIdx.x;
  const int h = bi >> 4;
  const int d0 = (bi & 15) << 6;
#pragma unroll
  for (int c = 0; c < 4; ++c) {
    const int dd = c * 16 + (tid >> 4);
    const int e4 = (tid & 15) << 2;
    float4 vq = *(const float4*)(W + (h << 16) + ((d0 + dd) << 6) + e4);
    *(float4*)(tile + dd * 68 + e4) = vq;
  }
  __syncthreads();
  {
    const int e = tid >> 2;
    const int dc = (tid & 3) << 4;
    alignas(16) u16 outv[16];
#pragma unroll
    for (int i = 0; i < 16; ++i) outv[i] = f2bf(tile[(dc + i) * 68 + e]);
    u16* dst = WT + (((size_t)(h << 6) + e) << 10) + d0 + dc;
    *(uint4*)(dst) = *(uint4*)outv;
    *(uint4*)(dst + 8) = *(uint4*)(outv + 8);
  }
}

// ---------------- GEMM core: C = A[4096,1024] * BT[1024,1024]^T + bias ----------------
// m97 structure: 128x128 tile, BK=64, 4 waves, global_load_lds w/ source preswizzle.
// mode 0: f32 row-major; 1: bf16 row-major; 2: bf16 transposed [col][row] (for VpT)
__device__ __forceinline__ void gemm_core(const u16* __restrict__ A,
                                          const u16* __restrict__ BT,
                                          const float* __restrict__ bias,
                                          void* __restrict__ Cout,
                                          float scale, int mode, int bi) {
  __shared__ u16 Al[128 * 64];
  __shared__ u16 Bl[128 * 64];
  const int tid = threadIdx.x;
  const int wave = tid >> 6;
  const int lane = tid & 63;
  const int l15 = lane & 15, lq = lane >> 4;
  const int bm = bi >> 3;
  const int bn = bi & 7;
  const int row0 = bm << 7, col0 = bn << 7;
  const int wr = ((wave >> 1) & 1) << 6;
  const int wc = (wave & 1) << 6;

  f32x4 acc[4][4];
#pragma unroll
  for (int m = 0; m < 4; ++m)
#pragma unroll
    for (int n = 0; n < 4; ++n) acc[m][n] = (f32x4)0.0f;

  for (int k0 = 0; k0 < 1024; k0 += 64) {
    __syncthreads();
#pragma unroll
    for (int c = 0; c < 4; ++c) {
      const int x = c * 4096 + tid * 16;
      const int g = x ^ (((x >> 7) & 7) << 4);
      const int row = g >> 7;
      const int cb = g & 127;
      const u16* ga = A + (size_t)(row0 + row) * 1024 + k0 + (cb >> 1);
      const u16* gb = BT + (size_t)(col0 + row) * 1024 + k0 + (cb >> 1);
      async16(ga, (char*)Al + c * 4096 + (wave << 10));
      async16(gb, (char*)Bl + c * 4096 + (wave << 10));
    }
    __syncthreads();

    bf16x8 af[4][2], bfr[4][2];
#pragma unroll
    for (int m = 0; m < 4; ++m)
#pragma unroll
      for (int kf = 0; kf < 2; ++kf) {
        int r = wr + m * 16 + l15;
        int byte = ((r << 7) + kf * 64 + lq * 16) ^ ((r & 7) << 4);
        af[m][kf] = *(const bf16x8*)((const char*)Al + byte);
      }
#pragma unroll
    for (int n = 0; n < 4; ++n)
#pragma unroll
      for (int kf = 0; kf < 2; ++kf) {
        int r = wc + n * 16 + l15;
        int byte = ((r << 7) + kf * 64 + lq * 16) ^ ((r & 7) << 4);
        bfr[n][kf] = *(const bf16x8*)((const char*)Bl + byte);
      }
#pragma unroll
    for (int kf = 0; kf < 2; ++kf)
#pragma unroll
      for (int m = 0; m < 4; ++m)
#pragma unroll
        for (int n = 0; n < 4; ++n)
          acc[m][n] = mfma16(af[m][kf], bfr[n][kf], acc[m][n]);
  }

#pragma unroll
  for (int m = 0; m < 4; ++m)
#pragma unroll
    for (int n = 0; n < 4; ++n) {
      int col = col0 + wc + n * 16 + l15;
      float bv = bias[col];
      int rowb = row0 + wr + m * 16 + lq * 4;
      if (mode == 2) {
        alignas(8) u16 r4[4];
#pragma unroll
        for (int j = 0; j < 4; ++j) r4[j] = f2bf((acc[m][n][j] + bv) * scale);
        *(uint2*)((u16*)Cout + (size_t)col * 4096 + rowb) = *(uint2*)r4;
      } else if (mode == 1) {
#pragma unroll
        for (int j = 0; j < 4; ++j)
          ((u16*)Cout)[(size_t)(rowb + j) * 1024 + col] = f2bf((acc[m][n][j] + bv) * scale);
      } else {
#pragma unroll
        for (int j = 0; j < 4; ++j)
          ((float*)Cout)[(size_t)(rowb + j) * 1024 + col] = (acc[m][n][j] + bv) * scale;
      }
    }
}

__global__ __launch_bounds__(256)
void gemm3(const u16* __restrict__ qb, const u16* __restrict__ kb, const u16* __restrict__ vb,
           const u16* __restrict__ Tq, const u16* __restrict__ Tk, const u16* __restrict__ Tv,
           const float* __restrict__ bq, const float* __restrict__ bk, const float* __restrict__ bv,
           u16* __restrict__ Qp, u16* __restrict__ Kp, u16* __restrict__ VpT) {
  const int g = blockIdx.x >> 8;
  const int bi = blockIdx.x & 255;
  const u16* A = g == 0 ? qb : (g == 1 ? kb : vb);
  const u16* BT = g == 0 ? Tq : (g == 1 ? Tk : Tv);
  const float* bias = g == 0 ? bq : (g == 1 ? bk : bv);
  void* out = g == 0 ? (void*)Qp : (g == 1 ? (void*)Kp : (void*)VpT);
  gemm_core(A, BT, bias, out, g == 0 ? 0.125f : 1.0f, g == 2 ? 2 : 1, bi);
}

__global__ __launch_bounds__(256)
void gemmO(const u16* __restrict__ A, const u16* __restrict__ BT,
           const float* __restrict__ bias, float* __restrict__ out) {
  gemm_core(A, BT, bias, out, 1.0f, 0, blockIdx.x);
}

// ---------------- flash attention v3b: swapped QK^T, in-register softmax ----------------
// grid B*H*(S/64); 4 waves x 16 q-rows. K [B,S,H,E]; V pre-transposed VpT [H*E][B*S].
// s = mfma(K_frag, Q_frag) => lane holds 16 scores of q = lane&15 (t = n*16+lq*4+j).
// Per-lane scalar m/l stats; defer-max THR=8; P packed via f2bf (cvt_pk asm removed: R4 suspect).
__global__ __launch_bounds__(256)
void attn(const u16* __restrict__ Qp, const u16* __restrict__ Kp,
          const u16* __restrict__ VpT, u16* __restrict__ Ow) {
  __shared__ alignas(16) u16 Kl[2][64 * 64];
  __shared__ alignas(16) u16 VTl[2][64 * 64];
  __shared__ alignas(16) u16 Pl[4][16 * 64];
  const int tid = threadIdx.x;
  const int wave = tid >> 6;
  const int lane = tid & 63;
  const int l15 = lane & 15, lq = lane >> 4;
  const int qt = blockIdx.x & 15;
  const int bh = blockIdx.x >> 4;
  const int b = bh >> 4, h = bh & 15;
  const size_t bS = (size_t)b * S_SZ;

  // staging source addresses (source-preswizzled; row bits unaffected by XOR)
  const int xs0 = tid * 16, xs1 = 4096 + tid * 16;
  const int r0 = xs0 >> 7, r1 = xs1 >> 7;
  const int c0 = ((xs0 & 127) ^ (((xs0 >> 7) & 7) << 4)) >> 1;
  const int c1 = ((xs1 & 127) ^ (((xs1 >> 7) & 7) << 4)) >> 1;
  const u16* Kb0 = Kp + ((bS + r0) << 10) + h * 64 + c0;
  const u16* Kb1 = Kp + ((bS + r1) << 10) + h * 64 + c1;
  const u16* Vb0 = VpT + (size_t)(h * 64 + r0) * 4096 + bS + c0;
  const u16* Vb1 = VpT + (size_t)(h * 64 + r1) * 4096 + bS + c1;

  bf16x8 aq[2];
  {
    const u16* qptr = Qp + ((bS + qt * 64 + wave * 16 + l15) << 10) + h * 64 + lq * 8;
    aq[0] = *(const bf16x8*)(qptr);
    aq[1] = *(const bf16x8*)(qptr + 32);
  }

  f32x4 o[4];
#pragma unroll
  for (int n = 0; n < 4; ++n) o[n] = (f32x4)0.0f;
  float m_run = -1e30f;   // per-lane: q = l15
  float l_run = 0.f;
  u16* Pw = Pl[wave];

  // prologue: stage tile 0
  async16(Kb0, (char*)Kl[0] + xs0);
  async16(Kb1, (char*)Kl[0] + xs1);
  async16(Vb0, (char*)VTl[0] + xs0);
  async16(Vb1, (char*)VTl[0] + xs1);
  __syncthreads();

  int buf = 0;
  for (int t0 = 0; t0 < S_SZ; t0 += 64) {
    // prefetch next tile into other buffer (drained by end-of-iter barrier)
    if (t0 + 64 < S_SZ) {
      const int tn = t0 + 64;
      async16(Kb0 + ((size_t)tn << 10), (char*)Kl[buf ^ 1] + xs0);
      async16(Kb1 + ((size_t)tn << 10), (char*)Kl[buf ^ 1] + xs1);
      async16(Vb0 + tn, (char*)VTl[buf ^ 1] + xs0);
      async16(Vb1 + tn, (char*)VTl[buf ^ 1] + xs1);
    }

    // swapped QK^T: s[n][j] = score[t = n*16+lq*4+j][q = l15]
    f32x4 s[4];
#pragma unroll
    for (int n = 0; n < 4; ++n) s[n] = (f32x4)0.0f;
#pragma unroll
    for (int n = 0; n < 4; ++n)
#pragma unroll
      for (int kf = 0; kf < 2; ++kf) {
        int r = n * 16 + l15;
        int byte = ((r << 7) + kf * 64 + lq * 16) ^ ((r & 7) << 4);
        bf16x8 bk = *(const bf16x8*)((const char*)Kl[buf] + byte);
        s[n] = mfma16(bk, aq[kf], s[n]);   // A=K rows(t), B=Q cols(q)
      }

    // in-lane row max over the 16 t-values, then cross the 4 lq-groups
    float mx = s[0][0];
#pragma unroll
    for (int n = 0; n < 4; ++n)
#pragma unroll
      for (int j = 0; j < 4; ++j) mx = fmaxf(mx, s[n][j]);
    mx = fmaxf(mx, __shfl_xor(mx, 16, 64));
    mx = fmaxf(mx, __shfl_xor(mx, 32, 64));

    // defer-max (T13): rescale only if some row max grew past m_run + 8
    if (__any(mx > m_run + 8.0f)) {
      float mn = fmaxf(m_run, mx);
      float alpha = __expf(m_run - mn);
      m_run = mn;
      l_run *= alpha;
      float a0 = __shfl(alpha, lq * 4 + 0, 64);
      float a1 = __shfl(alpha, lq * 4 + 1, 64);
      float a2 = __shfl(alpha, lq * 4 + 2, 64);
      float a3 = __shfl(alpha, lq * 4 + 3, 64);
#pragma unroll
      for (int n = 0; n < 4; ++n) {
        o[n][0] *= a0; o[n][1] *= a1; o[n][2] *= a2; o[n][3] *= a3;
      }
    }

    // P = exp(s - m_run); in-lane sum; pack bf16 pairs (f2bf); write to LDS
    float rs = 0.f;
#pragma unroll
    for (int n = 0; n < 4; ++n) {
      float p0 = __expf(s[n][0] - m_run);
      float p1 = __expf(s[n][1] - m_run);
      float p2 = __expf(s[n][2] - m_run);
      float p3 = __expf(s[n][3] - m_run);
      rs += (p0 + p1) + (p2 + p3);
      u32 lo = pack_bf16(p0, p1);
      u32 hi = pack_bf16(p2, p3);
      int byte = (l15 << 7) + (((n * 32 + lq * 8)) ^ ((l15 & 7) << 4));
      uint2 wv; wv.x = lo; wv.y = hi;
      *(uint2*)((char*)Pw + byte) = wv;
    }
    rs += __shfl_xor(rs, 16, 64);
    rs += __shfl_xor(rs, 32, 64);
    l_run += rs;

    // PV: A = P (row=q=l15, k=t), B = V^T rows (e) from LDS
#pragma unroll
    for (int kf = 0; kf < 2; ++kf) {
      int pbyte = (l15 << 7) + ((kf * 64 + lq * 16) ^ ((l15 & 7) << 4));
      bf16x8 pa = *(const bf16x8*)((const char*)Pw + pbyte);
#pragma unroll
      for (int n = 0; n < 4; ++n) {
        int vr = n * 16 + l15;
        int byte = ((vr << 7) + kf * 64 + lq * 16) ^ ((vr & 7) << 4);
        bf16x8 bv = *(const bf16x8*)((const char*)VTl[buf] + byte);
        o[n] = mfma16(pa, bv, o[n]);
      }
    }

    __syncthreads();   // drains this iter's prefetch (vmcnt) + syncs buffers
    buf ^= 1;
  }

  // broadcast per-q l_run (lives at lane l15=q) to output layout q = lq*4+j
  float li0 = __shfl(l_run, lq * 4 + 0, 64);
  float li1 = __shfl(l_run, lq * 4 + 1, 64);
  float li2 = __shfl(l_run, lq * 4 + 2, 64);
  float li3 = __shfl(l_run, lq * 4 + 3, 64);
  float inv0 = 1.0f / li0, inv1 = 1.0f / li1, inv2 = 1.0f / li2, inv3 = 1.0f / li3;
#pragma unroll
  for (int n = 0; n < 4; ++n) {
    float vals[4] = {o[n][0] * inv0, o[n][1] * inv1, o[n][2] * inv2, o[n][3] * inv3};
#pragma unroll
    for (int j = 0; j < 4; ++j) {
      int row = qt * 64 + wave * 16 + lq * 4 + j;
      int col = h * 64 + n * 16 + l15;
      Ow[((bS + row) << 10) + col] = f2bf(vals[j]);
    }
  }
}

extern "C" void kernel_launch(void* const* d_in, const int* in_sizes, int n_in,
                              void* d_out, int out_size, void* d_ws, size_t ws_size,
                              hipStream_t stream) {
  const float* q  = (const float*)d_in[0];
  const float* k  = (const float*)d_in[1];
  const float* v  = (const float*)d_in[2];
  const float* Wq = (const float*)d_in[3];
  const float* bq = (const float*)d_in[4];
  const float* Wk = (const float*)d_in[5];
  const float* bk = (const float*)d_in[6];
  const float* Wv = (const float*)d_in[7];
  const float* bv = (const float*)d_in[8];
  const float* Wo = (const float*)d_in[9];
  const float* bo = (const float*)d_in[10];

  char* w = (char*)d_ws;
  const size_t MB = 1u << 20;
  u16* qb  = (u16*)(w + 0 * MB);
  u16* kb  = (u16*)(w + 8 * MB);
  u16* vb  = (u16*)(w + 16 * MB);
  u16* WqT = (u16*)(w + 24 * MB);
  u16* WkT = (u16*)(w + 26 * MB);
  u16* WvT = (u16*)(w + 28 * MB);
  u16* Wob = (u16*)(w + 30 * MB);
  u16* Qp  = (u16*)(w + 32 * MB);
  u16* Kp  = (u16*)(w + 40 * MB);
  u16* VpT = (u16*)(w + 48 * MB);
  u16* wvb = (u16*)(w + 56 * MB);

  const int nW = H_SZ * D_SZ * E_SZ;     // 1M

  cast3<<<6144, 256, 0, stream>>>(q, k, v, qb, kb, vb);
  cast_bf16_k<<<nW / 2048, 256, 0, stream>>>(Wo, Wob, nW);
  transW3<<<768, 256, 0, stream>>>(Wq, Wk, Wv, WqT, WkT, WvT);

  gemm3<<<768, 256, 0, stream>>>(qb, kb, vb, WqT, WkT, WvT, bq, bk, bv, Qp, Kp, VpT);

  attn<<<B_SZ * H_SZ * (S_SZ / 64), 256, 0, stream>>>(Qp, Kp, VpT, wvb);

  gemmO<<<256, 256, 0, stream>>>(wvb, Wob, bo, (float*)d_out);
}

// Round 6
// 127.082 us; speedup vs baseline: 1.5918x; 1.0541x over previous
//
#include <hip/hip_runtime.h>

typedef unsigned short u16;
typedef unsigned int u32;
typedef __attribute__((ext_vector_type(8))) short bf16x8;
typedef __attribute__((ext_vector_type(4))) float f32x4;

#define B_SZ 4
#define S_SZ 1024
#define D_SZ 1024
#define H_SZ 16
#define E_SZ 64
#define M_SZ (B_SZ * S_SZ)   // 4096

__device__ __forceinline__ u16 f2bf(float f) {
  union { float f; unsigned u; } x; x.f = f;
  unsigned r = (x.u + 0x7FFFu + ((x.u >> 16) & 1u)) >> 16;
  return (u16)r;
}

__device__ __forceinline__ u32 pack_bf16(float lo, float hi) {
  return (u32)f2bf(lo) | ((u32)f2bf(hi) << 16);
}

__device__ __forceinline__ void async16(const void* g, void* l) {
  __builtin_amdgcn_global_load_lds(
      (const __attribute__((address_space(1))) void*)g,
      (__attribute__((address_space(3))) void*)l, 16, 0, 0);
}

__device__ __forceinline__ f32x4 mfma16(bf16x8 a, bf16x8 b, f32x4 c) {
  return __builtin_amdgcn_mfma_f32_16x16x32_bf16(a, b, c, 0, 0, 0);
}

// ---------------- fused cast f32 -> bf16 for q,k,v,Wo ----------------
__global__ void cast4(const float* __restrict__ q, const float* __restrict__ k,
                      const float* __restrict__ v, const float* __restrict__ Wo,
                      u16* __restrict__ oq, u16* __restrict__ ok,
                      u16* __restrict__ ov, u16* __restrict__ oWo) {
  int gid = blockIdx.x * 256 + threadIdx.x;
  const float* in;
  u16* out;
  int i;
  if (gid < (3 << 19)) {
    int sel = gid >> 19;
    i = (gid & ((1 << 19) - 1)) << 3;
    in = sel == 0 ? q : (sel == 1 ? k : v);
    out = sel == 0 ? oq : (sel == 1 ? ok : ov);
  } else {
    i = (gid - (3 << 19)) << 3;
    in = Wo;
    out = oWo;
  }
  float4 a = *(const float4*)(in + i);
  float4 b = *(const float4*)(in + i + 4);
  alignas(16) u16 r[8];
  r[0] = f2bf(a.x); r[1] = f2bf(a.y); r[2] = f2bf(a.z); r[3] = f2bf(a.w);
  r[4] = f2bf(b.x); r[5] = f2bf(b.y); r[6] = f2bf(b.z); r[7] = f2bf(b.w);
  *(uint4*)(out + i) = *(uint4*)r;
}

// ------------- fused W [H,D,E] f32 -> WT [H*E, D] bf16 for Wq,Wk,Wv -------------
__global__ void transW3(const float* __restrict__ Wq, const float* __restrict__ Wk,
                        const float* __restrict__ Wv, u16* __restrict__ Tq,
                        u16* __restrict__ Tk, u16* __restrict__ Tv) {
  __shared__ float tile[64 * 68];
  const int wsel = blockIdx.x >> 8;
  const int bi = blockIdx.x & 255;
  const float* W = wsel == 0 ? Wq : (wsel == 1 ? Wk : Wv);
  u16* WT = wsel == 0 ? Tq : (wsel == 1 ? Tk : Tv);
  const int tid = threadIdx.x;
  const int h = bi >> 4;
  const int d0 = (bi & 15) << 6;
#pragma unroll
  for (int c = 0; c < 4; ++c) {
    const int dd = c * 16 + (tid >> 4);
    const int e4 = (tid & 15) << 2;
    float4 vq = *(const float4*)(W + (h << 16) + ((d0 + dd) << 6) + e4);
    *(float4*)(tile + dd * 68 + e4) = vq;
  }
  __syncthreads();
  {
    const int e = tid >> 2;
    const int dc = (tid & 3) << 4;
    alignas(16) u16 outv[16];
#pragma unroll
    for (int i = 0; i < 16; ++i) outv[i] = f2bf(tile[(dc + i) * 68 + e]);
    u16* dst = WT + (((size_t)(h << 6) + e) << 10) + d0 + dc;
    *(uint4*)(dst) = *(uint4*)outv;
    *(uint4*)(dst + 8) = *(uint4*)(outv + 8);
  }
}

// ---------------- fused QKV projection GEMM ----------------
// 768 blocks: g = bi>>8 selects {Q, K, V}. 128x128 tile, BK=64, 4 waves.
// g<2: swapped acc (C^T in regs) -> vectorized uint2 row-major stores.
// g==2: unswapped -> transposed [col][row] uint2 stores (VpT).
__global__ __launch_bounds__(256)
void gemm3(const u16* __restrict__ qb, const u16* __restrict__ kb, const u16* __restrict__ vb,
           const u16* __restrict__ Tq, const u16* __restrict__ Tk, const u16* __restrict__ Tv,
           const float* __restrict__ bq, const float* __restrict__ bk, const float* __restrict__ bv,
           u16* __restrict__ Qp, u16* __restrict__ Kp, u16* __restrict__ VpT) {
  __shared__ u16 Al[128 * 64];
  __shared__ u16 Bl[128 * 64];
  const int g = blockIdx.x >> 8;
  const int bi = blockIdx.x & 255;
  const u16* A = g == 0 ? qb : (g == 1 ? kb : vb);
  const u16* BT = g == 0 ? Tq : (g == 1 ? Tk : Tv);
  const float* bias = g == 0 ? bq : (g == 1 ? bk : bv);
  u16* Cout = g == 0 ? Qp : (g == 1 ? Kp : VpT);
  const float scale = g == 0 ? 0.125f : 1.0f;

  const int tid = threadIdx.x;
  const int wave = tid >> 6;
  const int lane = tid & 63;
  const int l15 = lane & 15, lq = lane >> 4;
  const int bm = bi >> 3;
  const int bn = bi & 7;
  const int row0 = bm << 7, col0 = bn << 7;
  const int wr = ((wave >> 1) & 1) << 6;
  const int wc = (wave & 1) << 6;

  f32x4 acc[4][4];
#pragma unroll
  for (int m = 0; m < 4; ++m)
#pragma unroll
    for (int n = 0; n < 4; ++n) acc[m][n] = (f32x4)0.0f;

  for (int k0 = 0; k0 < 1024; k0 += 64) {
    __syncthreads();
#pragma unroll
    for (int c = 0; c < 4; ++c) {
      const int x = c * 4096 + tid * 16;
      const int gx = x ^ (((x >> 7) & 7) << 4);
      const int row = gx >> 7;
      const int cb = gx & 127;
      const u16* ga = A + (size_t)(row0 + row) * 1024 + k0 + (cb >> 1);
      const u16* gb = BT + (size_t)(col0 + row) * 1024 + k0 + (cb >> 1);
      async16(ga, (char*)Al + x);
      async16(gb, (char*)Bl + x);
    }
    __syncthreads();

    bf16x8 af[4][2], bfr[4][2];
#pragma unroll
    for (int m = 0; m < 4; ++m)
#pragma unroll
      for (int kf = 0; kf < 2; ++kf) {
        int r = wr + m * 16 + l15;
        int byte = ((r << 7) + kf * 64 + lq * 16) ^ ((r & 7) << 4);
        af[m][kf] = *(const bf16x8*)((const char*)Al + byte);
      }
#pragma unroll
    for (int n = 0; n < 4; ++n)
#pragma unroll
      for (int kf = 0; kf < 2; ++kf) {
        int r = wc + n * 16 + l15;
        int byte = ((r << 7) + kf * 64 + lq * 16) ^ ((r & 7) << 4);
        bfr[n][kf] = *(const bf16x8*)((const char*)Bl + byte);
      }
    if (g == 2) {
#pragma unroll
      for (int kf = 0; kf < 2; ++kf)
#pragma unroll
        for (int m = 0; m < 4; ++m)
#pragma unroll
          for (int n = 0; n < 4; ++n)
            acc[m][n] = mfma16(af[m][kf], bfr[n][kf], acc[m][n]);
    } else {
#pragma unroll
      for (int kf = 0; kf < 2; ++kf)
#pragma unroll
        for (int m = 0; m < 4; ++m)
#pragma unroll
          for (int n = 0; n < 4; ++n)
            acc[m][n] = mfma16(bfr[n][kf], af[m][kf], acc[m][n]);
    }
  }

  if (g == 2) {
    // unswapped: lane holds col=col0+wc+n*16+l15, rows rowb..rowb+3 -> VpT [col][row]
#pragma unroll
    for (int m = 0; m < 4; ++m)
#pragma unroll
      for (int n = 0; n < 4; ++n) {
        int col = col0 + wc + n * 16 + l15;
        float bv = bias[col];
        int rowb = row0 + wr + m * 16 + lq * 4;
        alignas(8) u16 r4[4];
#pragma unroll
        for (int j = 0; j < 4; ++j) r4[j] = f2bf(acc[m][n][j] + bv);
        *(uint2*)(Cout + (size_t)col * 4096 + rowb) = *(uint2*)r4;
      }
  } else {
    // swapped: lane holds row=row0+wr+m*16+l15, 4 consecutive cols
    float4 b4[4];
#pragma unroll
    for (int n = 0; n < 4; ++n)
      b4[n] = *(const float4*)(bias + col0 + wc + n * 16 + lq * 4);
#pragma unroll
    for (int m = 0; m < 4; ++m) {
      int row = row0 + wr + m * 16 + l15;
#pragma unroll
      for (int n = 0; n < 4; ++n) {
        int colbase = col0 + wc + n * 16 + lq * 4;
        u32 lo = pack_bf16((acc[m][n][0] + b4[n].x) * scale,
                           (acc[m][n][1] + b4[n].y) * scale);
        u32 hi = pack_bf16((acc[m][n][2] + b4[n].z) * scale,
                           (acc[m][n][3] + b4[n].w) * scale);
        uint2 wv; wv.x = lo; wv.y = hi;
        *(uint2*)(Cout + (size_t)row * 1024 + colbase) = wv;
      }
    }
  }
}

// ---------------- output GEMM: 8 waves/block (2 waves/SIMD at 1 block/CU) ----------------
// 128x128 tile, waves 4x2 (wr=(wave>>1)*32, wc=(wave&1)*64), acc[2][4], swapped.
__global__ __launch_bounds__(512)
void gemmO8(const u16* __restrict__ A, const u16* __restrict__ BT,
            const float* __restrict__ bias, float* __restrict__ out) {
  __shared__ u16 Al[128 * 64];
  __shared__ u16 Bl[128 * 64];
  const int tid = threadIdx.x;
  const int wave = tid >> 6;
  const int lane = tid & 63;
  const int l15 = lane & 15, lq = lane >> 4;
  const int bi = blockIdx.x;
  const int bm = bi >> 3;
  const int bn = bi & 7;
  const int row0 = bm << 7, col0 = bn << 7;
  const int wr = (wave >> 1) << 5;   // 0,32,64,96
  const int wc = (wave & 1) << 6;    // 0,64

  f32x4 acc[2][4];
#pragma unroll
  for (int m = 0; m < 2; ++m)
#pragma unroll
    for (int n = 0; n < 4; ++n) acc[m][n] = (f32x4)0.0f;

  for (int k0 = 0; k0 < 1024; k0 += 64) {
    __syncthreads();
#pragma unroll
    for (int c = 0; c < 2; ++c) {
      const int x = c * 8192 + tid * 16;
      const int gx = x ^ (((x >> 7) & 7) << 4);
      const int row = gx >> 7;
      const int cb = gx & 127;
      const u16* ga = A + (size_t)(row0 + row) * 1024 + k0 + (cb >> 1);
      const u16* gb = BT + (size_t)(col0 + row) * 1024 + k0 + (cb >> 1);
      async16(ga, (char*)Al + x);
      async16(gb, (char*)Bl + x);
    }
    __syncthreads();

    bf16x8 af[2][2], bfr[4][2];
#pragma unroll
    for (int m = 0; m < 2; ++m)
#pragma unroll
      for (int kf = 0; kf < 2; ++kf) {
        int r = wr + m * 16 + l15;
        int byte = ((r << 7) + kf * 64 + lq * 16) ^ ((r & 7) << 4);
        af[m][kf] = *(const bf16x8*)((const char*)Al + byte);
      }
#pragma unroll
    for (int n = 0; n < 4; ++n)
#pragma unroll
      for (int kf = 0; kf < 2; ++kf) {
        int r = wc + n * 16 + l15;
        int byte = ((r << 7) + kf * 64 + lq * 16) ^ ((r & 7) << 4);
        bfr[n][kf] = *(const bf16x8*)((const char*)Bl + byte);
      }
#pragma unroll
    for (int kf = 0; kf < 2; ++kf)
#pragma unroll
      for (int m = 0; m < 2; ++m)
#pragma unroll
        for (int n = 0; n < 4; ++n)
          acc[m][n] = mfma16(bfr[n][kf], af[m][kf], acc[m][n]);
  }

  float4 b4[4];
#pragma unroll
  for (int n = 0; n < 4; ++n)
    b4[n] = *(const float4*)(bias + col0 + wc + n * 16 + lq * 4);
#pragma unroll
  for (int m = 0; m < 2; ++m) {
    int row = row0 + wr + m * 16 + l15;
#pragma unroll
    for (int n = 0; n < 4; ++n) {
      int colbase = col0 + wc + n * 16 + lq * 4;
      float4 v;
      v.x = acc[m][n][0] + b4[n].x;
      v.y = acc[m][n][1] + b4[n].y;
      v.z = acc[m][n][2] + b4[n].z;
      v.w = acc[m][n][3] + b4[n].w;
      *(float4*)(out + (size_t)row * 1024 + colbase) = v;
    }
  }
}

// ---------------- flash attention v3b + setprio (T5) ----------------
__global__ __launch_bounds__(256)
void attn(const u16* __restrict__ Qp, const u16* __restrict__ Kp,
          const u16* __restrict__ VpT, u16* __restrict__ Ow) {
  __shared__ alignas(16) u16 Kl[2][64 * 64];
  __shared__ alignas(16) u16 VTl[2][64 * 64];
  __shared__ alignas(16) u16 Pl[4][16 * 64];
  const int tid = threadIdx.x;
  const int wave = tid >> 6;
  const int lane = tid & 63;
  const int l15 = lane & 15, lq = lane >> 4;
  const int qt = blockIdx.x & 15;
  const int bh = blockIdx.x >> 4;
  const int b = bh >> 4, h = bh & 15;
  const size_t bS = (size_t)b * S_SZ;

  const int xs0 = tid * 16, xs1 = 4096 + tid * 16;
  const int r0 = xs0 >> 7, r1 = xs1 >> 7;
  const int c0 = ((xs0 & 127) ^ (((xs0 >> 7) & 7) << 4)) >> 1;
  const int c1 = ((xs1 & 127) ^ (((xs1 >> 7) & 7) << 4)) >> 1;
  const u16* Kb0 = Kp + ((bS + r0) << 10) + h * 64 + c0;
  const u16* Kb1 = Kp + ((bS + r1) << 10) + h * 64 + c1;
  const u16* Vb0 = VpT + (size_t)(h * 64 + r0) * 4096 + bS + c0;
  const u16* Vb1 = VpT + (size_t)(h * 64 + r1) * 4096 + bS + c1;

  bf16x8 aq[2];
  {
    const u16* qptr = Qp + ((bS + qt * 64 + wave * 16 + l15) << 10) + h * 64 + lq * 8;
    aq[0] = *(const bf16x8*)(qptr);
    aq[1] = *(const bf16x8*)(qptr + 32);
  }

  f32x4 o[4];
#pragma unroll
  for (int n = 0; n < 4; ++n) o[n] = (f32x4)0.0f;
  float m_run = -1e30f;   // per-lane: q = l15
  float l_run = 0.f;
  u16* Pw = Pl[wave];

  async16(Kb0, (char*)Kl[0] + xs0);
  async16(Kb1, (char*)Kl[0] + xs1);
  async16(Vb0, (char*)VTl[0] + xs0);
  async16(Vb1, (char*)VTl[0] + xs1);
  __syncthreads();

  int buf = 0;
  for (int t0 = 0; t0 < S_SZ; t0 += 64) {
    if (t0 + 64 < S_SZ) {
      const int tn = t0 + 64;
      async16(Kb0 + ((size_t)tn << 10), (char*)Kl[buf ^ 1] + xs0);
      async16(Kb1 + ((size_t)tn << 10), (char*)Kl[buf ^ 1] + xs1);
      async16(Vb0 + tn, (char*)VTl[buf ^ 1] + xs0);
      async16(Vb1 + tn, (char*)VTl[buf ^ 1] + xs1);
    }

    // swapped QK^T: s[n][j] = score[t = n*16+lq*4+j][q = l15]
    f32x4 s[4];
#pragma unroll
    for (int n = 0; n < 4; ++n) s[n] = (f32x4)0.0f;
    __builtin_amdgcn_s_setprio(1);
#pragma unroll
    for (int n = 0; n < 4; ++n)
#pragma unroll
      for (int kf = 0; kf < 2; ++kf) {
        int r = n * 16 + l15;
        int byte = ((r << 7) + kf * 64 + lq * 16) ^ ((r & 7) << 4);
        bf16x8 bk = *(const bf16x8*)((const char*)Kl[buf] + byte);
        s[n] = mfma16(bk, aq[kf], s[n]);
      }
    __builtin_amdgcn_s_setprio(0);

    float mx = s[0][0];
#pragma unroll
    for (int n = 0; n < 4; ++n)
#pragma unroll
      for (int j = 0; j < 4; ++j) mx = fmaxf(mx, s[n][j]);
    mx = fmaxf(mx, __shfl_xor(mx, 16, 64));
    mx = fmaxf(mx, __shfl_xor(mx, 32, 64));

    if (__any(mx > m_run + 8.0f)) {
      float mn = fmaxf(m_run, mx);
      float alpha = __expf(m_run - mn);
      m_run = mn;
      l_run *= alpha;
      float a0 = __shfl(alpha, lq * 4 + 0, 64);
      float a1 = __shfl(alpha, lq * 4 + 1, 64);
      float a2 = __shfl(alpha, lq * 4 + 2, 64);
      float a3 = __shfl(alpha, lq * 4 + 3, 64);
#pragma unroll
      for (int n = 0; n < 4; ++n) {
        o[n][0] *= a0; o[n][1] *= a1; o[n][2] *= a2; o[n][3] *= a3;
      }
    }

    float rs = 0.f;
#pragma unroll
    for (int n = 0; n < 4; ++n) {
      float p0 = __expf(s[n][0] - m_run);
      float p1 = __expf(s[n][1] - m_run);
      float p2 = __expf(s[n][2] - m_run);
      float p3 = __expf(s[n][3] - m_run);
      rs += (p0 + p1) + (p2 + p3);
      u32 lo = pack_bf16(p0, p1);
      u32 hi = pack_bf16(p2, p3);
      int byte = (l15 << 7) + (((n * 32 + lq * 8)) ^ ((l15 & 7) << 4));
      uint2 wv; wv.x = lo; wv.y = hi;
      *(uint2*)((char*)Pw + byte) = wv;
    }
    rs += __shfl_xor(rs, 16, 64);
    rs += __shfl_xor(rs, 32, 64);
    l_run += rs;

    // PV: A = P (row=q=l15, k=t), B = V^T rows (e) from LDS
    __builtin_amdgcn_s_setprio(1);
#pragma unroll
    for (int kf = 0; kf < 2; ++kf) {
      int pbyte = (l15 << 7) + ((kf * 64 + lq * 16) ^ ((l15 & 7) << 4));
      bf16x8 pa = *(const bf16x8*)((const char*)Pw + pbyte);
#pragma unroll
      for (int n = 0; n < 4; ++n) {
        int vr = n * 16 + l15;
        int byte = ((vr << 7) + kf * 64 + lq * 16) ^ ((vr & 7) << 4);
        bf16x8 bv = *(const bf16x8*)((const char*)VTl[buf] + byte);
        o[n] = mfma16(pa, bv, o[n]);
      }
    }
    __builtin_amdgcn_s_setprio(0);

    __syncthreads();
    buf ^= 1;
  }

  float li0 = __shfl(l_run, lq * 4 + 0, 64);
  float li1 = __shfl(l_run, lq * 4 + 1, 64);
  float li2 = __shfl(l_run, lq * 4 + 2, 64);
  float li3 = __shfl(l_run, lq * 4 + 3, 64);
  float inv0 = 1.0f / li0, inv1 = 1.0f / li1, inv2 = 1.0f / li2, inv3 = 1.0f / li3;
#pragma unroll
  for (int n = 0; n < 4; ++n) {
    float vals[4] = {o[n][0] * inv0, o[n][1] * inv1, o[n][2] * inv2, o[n][3] * inv3};
#pragma unroll
    for (int j = 0; j < 4; ++j) {
      int row = qt * 64 + wave * 16 + lq * 4 + j;
      int col = h * 64 + n * 16 + l15;
      Ow[((bS + row) << 10) + col] = f2bf(vals[j]);
    }
  }
}

extern "C" void kernel_launch(void* const* d_in, const int* in_sizes, int n_in,
                              void* d_out, int out_size, void* d_ws, size_t ws_size,
                              hipStream_t stream) {
  const float* q  = (const float*)d_in[0];
  const float* k  = (const float*)d_in[1];
  const float* v  = (const float*)d_in[2];
  const float* Wq = (const float*)d_in[3];
  const float* bq = (const float*)d_in[4];
  const float* Wk = (const float*)d_in[5];
  const float* bk = (const float*)d_in[6];
  const float* Wv = (const float*)d_in[7];
  const float* bv = (const float*)d_in[8];
  const float* Wo = (const float*)d_in[9];
  const float* bo = (const float*)d_in[10];

  char* w = (char*)d_ws;
  const size_t MB = 1u << 20;
  u16* qb  = (u16*)(w + 0 * MB);
  u16* kb  = (u16*)(w + 8 * MB);
  u16* vb  = (u16*)(w + 16 * MB);
  u16* WqT = (u16*)(w + 24 * MB);
  u16* WkT = (u16*)(w + 26 * MB);
  u16* WvT = (u16*)(w + 28 * MB);
  u16* Wob = (u16*)(w + 30 * MB);
  u16* Qp  = (u16*)(w + 32 * MB);
  u16* Kp  = (u16*)(w + 40 * MB);
  u16* VpT = (u16*)(w + 48 * MB);
  u16* wvb = (u16*)(w + 56 * MB);

  cast4<<<6656, 256, 0, stream>>>(q, k, v, Wo, qb, kb, vb, Wob);
  transW3<<<768, 256, 0, stream>>>(Wq, Wk, Wv, WqT, WkT, WvT);

  gemm3<<<768, 256, 0, stream>>>(qb, kb, vb, WqT, WkT, WvT, bq, bk, bv, Qp, Kp, VpT);

  attn<<<B_SZ * H_SZ * (S_SZ / 64), 256, 0, stream>>>(Qp, Kp, VpT, wvb);

  gemmO8<<<256, 512, 0, stream>>>(wvb, Wob, bo, (float*)d_out);
}

// Round 7
// 122.438 us; speedup vs baseline: 1.6522x; 1.0379x over previous
//
#include <hip/hip_runtime.h>

typedef unsigned short u16;
typedef unsigned int u32;
typedef __attribute__((ext_vector_type(8))) short bf16x8;
typedef __attribute__((ext_vector_type(4))) float f32x4;

#define B_SZ 4
#define S_SZ 1024
#define D_SZ 1024
#define H_SZ 16
#define E_SZ 64
#define M_SZ (B_SZ * S_SZ)   // 4096

__device__ __forceinline__ u16 f2bf(float f) {
  union { float f; unsigned u; } x; x.f = f;
  unsigned r = (x.u + 0x7FFFu + ((x.u >> 16) & 1u)) >> 16;
  return (u16)r;
}

__device__ __forceinline__ u32 pack_bf16(float lo, float hi) {
  return (u32)f2bf(lo) | ((u32)f2bf(hi) << 16);
}

__device__ __forceinline__ void async16(const void* g, void* l) {
  __builtin_amdgcn_global_load_lds(
      (const __attribute__((address_space(1))) void*)g,
      (__attribute__((address_space(3))) void*)l, 16, 0, 0);
}

__device__ __forceinline__ f32x4 mfma16(bf16x8 a, bf16x8 b, f32x4 c) {
  return __builtin_amdgcn_mfma_f32_16x16x32_bf16(a, b, c, 0, 0, 0);
}

// ---------------- fused cast f32 -> bf16 for q,k,v,Wo ----------------
__global__ void cast4(const float* __restrict__ q, const float* __restrict__ k,
                      const float* __restrict__ v, const float* __restrict__ Wo,
                      u16* __restrict__ oq, u16* __restrict__ ok,
                      u16* __restrict__ ov, u16* __restrict__ oWo) {
  int gid = blockIdx.x * 256 + threadIdx.x;
  const float* in;
  u16* out;
  int i;
  if (gid < (3 << 19)) {
    int sel = gid >> 19;
    i = (gid & ((1 << 19) - 1)) << 3;
    in = sel == 0 ? q : (sel == 1 ? k : v);
    out = sel == 0 ? oq : (sel == 1 ? ok : ov);
  } else {
    i = (gid - (3 << 19)) << 3;
    in = Wo;
    out = oWo;
  }
  float4 a = *(const float4*)(in + i);
  float4 b = *(const float4*)(in + i + 4);
  alignas(16) u16 r[8];
  r[0] = f2bf(a.x); r[1] = f2bf(a.y); r[2] = f2bf(a.z); r[3] = f2bf(a.w);
  r[4] = f2bf(b.x); r[5] = f2bf(b.y); r[6] = f2bf(b.z); r[7] = f2bf(b.w);
  *(uint4*)(out + i) = *(uint4*)r;
}

// ------------- fused W [H,D,E] f32 -> WT [H*E, D] bf16 for Wq,Wk,Wv -------------
__global__ void transW3(const float* __restrict__ Wq, const float* __restrict__ Wk,
                        const float* __restrict__ Wv, u16* __restrict__ Tq,
                        u16* __restrict__ Tk, u16* __restrict__ Tv) {
  __shared__ float tile[64 * 68];
  const int wsel = blockIdx.x >> 8;
  const int bi = blockIdx.x & 255;
  const float* W = wsel == 0 ? Wq : (wsel == 1 ? Wk : Wv);
  u16* WT = wsel == 0 ? Tq : (wsel == 1 ? Tk : Tv);
  const int tid = threadIdx.x;
  const int h = bi >> 4;
  const int d0 = (bi & 15) << 6;
#pragma unroll
  for (int c = 0; c < 4; ++c) {
    const int dd = c * 16 + (tid >> 4);
    const int e4 = (tid & 15) << 2;
    float4 vq = *(const float4*)(W + (h << 16) + ((d0 + dd) << 6) + e4);
    *(float4*)(tile + dd * 68 + e4) = vq;
  }
  __syncthreads();
  {
    const int e = tid >> 2;
    const int dc = (tid & 3) << 4;
    alignas(16) u16 outv[16];
#pragma unroll
    for (int i = 0; i < 16; ++i) outv[i] = f2bf(tile[(dc + i) * 68 + e]);
    u16* dst = WT + (((size_t)(h << 6) + e) << 10) + d0 + dc;
    *(uint4*)(dst) = *(uint4*)outv;
    *(uint4*)(dst + 8) = *(uint4*)(outv + 8);
  }
}

// ---------------- fused QKV projection GEMM (T1 XCD-chunked swizzle) ----------------
// 768 blocks: logical = (hw%8)*96 + hw/8 -> XCD k owns logical [96k, 96k+96):
// one sub-GEMM's weight (2MB) stays hot in that XCD's L2; A-panels reused across bn.
__global__ __launch_bounds__(256)
void gemm3(const u16* __restrict__ qb, const u16* __restrict__ kb, const u16* __restrict__ vb,
           const u16* __restrict__ Tq, const u16* __restrict__ Tk, const u16* __restrict__ Tv,
           const float* __restrict__ bq, const float* __restrict__ bk, const float* __restrict__ bv,
           u16* __restrict__ Qp, u16* __restrict__ Kp, u16* __restrict__ VpT) {
  __shared__ u16 Al[128 * 64];
  __shared__ u16 Bl[128 * 64];
  const int wg = blockIdx.x;
  const int swz = (wg & 7) * 96 + (wg >> 3);   // T1: bijective (768 % 8 == 0)
  const int g = swz >> 8;
  const int bi = swz & 255;
  const u16* A = g == 0 ? qb : (g == 1 ? kb : vb);
  const u16* BT = g == 0 ? Tq : (g == 1 ? Tk : Tv);
  const float* bias = g == 0 ? bq : (g == 1 ? bk : bv);
  u16* Cout = g == 0 ? Qp : (g == 1 ? Kp : VpT);
  const float scale = g == 0 ? 0.125f : 1.0f;

  const int tid = threadIdx.x;
  const int wave = tid >> 6;
  const int lane = tid & 63;
  const int l15 = lane & 15, lq = lane >> 4;
  const int bm = bi >> 3;
  const int bn = bi & 7;
  const int row0 = bm << 7, col0 = bn << 7;
  const int wr = ((wave >> 1) & 1) << 6;
  const int wc = (wave & 1) << 6;

  f32x4 acc[4][4];
#pragma unroll
  for (int m = 0; m < 4; ++m)
#pragma unroll
    for (int n = 0; n < 4; ++n) acc[m][n] = (f32x4)0.0f;

  for (int k0 = 0; k0 < 1024; k0 += 64) {
    __syncthreads();
#pragma unroll
    for (int c = 0; c < 4; ++c) {
      const int x = c * 4096 + tid * 16;
      const int gx = x ^ (((x >> 7) & 7) << 4);
      const int row = gx >> 7;
      const int cb = gx & 127;
      const u16* ga = A + (size_t)(row0 + row) * 1024 + k0 + (cb >> 1);
      const u16* gb = BT + (size_t)(col0 + row) * 1024 + k0 + (cb >> 1);
      async16(ga, (char*)Al + x);
      async16(gb, (char*)Bl + x);
    }
    __syncthreads();

    bf16x8 af[4][2], bfr[4][2];
#pragma unroll
    for (int m = 0; m < 4; ++m)
#pragma unroll
      for (int kf = 0; kf < 2; ++kf) {
        int r = wr + m * 16 + l15;
        int byte = ((r << 7) + kf * 64 + lq * 16) ^ ((r & 7) << 4);
        af[m][kf] = *(const bf16x8*)((const char*)Al + byte);
      }
#pragma unroll
    for (int n = 0; n < 4; ++n)
#pragma unroll
      for (int kf = 0; kf < 2; ++kf) {
        int r = wc + n * 16 + l15;
        int byte = ((r << 7) + kf * 64 + lq * 16) ^ ((r & 7) << 4);
        bfr[n][kf] = *(const bf16x8*)((const char*)Bl + byte);
      }
    if (g == 2) {
#pragma unroll
      for (int kf = 0; kf < 2; ++kf)
#pragma unroll
        for (int m = 0; m < 4; ++m)
#pragma unroll
          for (int n = 0; n < 4; ++n)
            acc[m][n] = mfma16(af[m][kf], bfr[n][kf], acc[m][n]);
    } else {
#pragma unroll
      for (int kf = 0; kf < 2; ++kf)
#pragma unroll
        for (int m = 0; m < 4; ++m)
#pragma unroll
          for (int n = 0; n < 4; ++n)
            acc[m][n] = mfma16(bfr[n][kf], af[m][kf], acc[m][n]);
    }
  }

  if (g == 2) {
    // unswapped: lane holds col=col0+wc+n*16+l15, rows rowb..rowb+3 -> VpT [col][row]
#pragma unroll
    for (int m = 0; m < 4; ++m)
#pragma unroll
      for (int n = 0; n < 4; ++n) {
        int col = col0 + wc + n * 16 + l15;
        float bv = bias[col];
        int rowb = row0 + wr + m * 16 + lq * 4;
        alignas(8) u16 r4[4];
#pragma unroll
        for (int j = 0; j < 4; ++j) r4[j] = f2bf(acc[m][n][j] + bv);
        *(uint2*)(Cout + (size_t)col * 4096 + rowb) = *(uint2*)r4;
      }
  } else {
    // swapped: lane holds row=row0+wr+m*16+l15, 4 consecutive cols
    float4 b4[4];
#pragma unroll
    for (int n = 0; n < 4; ++n)
      b4[n] = *(const float4*)(bias + col0 + wc + n * 16 + lq * 4);
#pragma unroll
    for (int m = 0; m < 4; ++m) {
      int row = row0 + wr + m * 16 + l15;
#pragma unroll
      for (int n = 0; n < 4; ++n) {
        int colbase = col0 + wc + n * 16 + lq * 4;
        u32 lo = pack_bf16((acc[m][n][0] + b4[n].x) * scale,
                           (acc[m][n][1] + b4[n].y) * scale);
        u32 hi = pack_bf16((acc[m][n][2] + b4[n].z) * scale,
                           (acc[m][n][3] + b4[n].w) * scale);
        uint2 wv; wv.x = lo; wv.y = hi;
        *(uint2*)(Cout + (size_t)row * 1024 + colbase) = wv;
      }
    }
  }
}

// ---------------- output GEMM: 8 waves/block + T1 swizzle ----------------
__global__ __launch_bounds__(512)
void gemmO8(const u16* __restrict__ A, const u16* __restrict__ BT,
            const float* __restrict__ bias, float* __restrict__ out) {
  __shared__ u16 Al[128 * 64];
  __shared__ u16 Bl[128 * 64];
  const int tid = threadIdx.x;
  const int wave = tid >> 6;
  const int lane = tid & 63;
  const int l15 = lane & 15, lq = lane >> 4;
  const int wg = blockIdx.x;
  const int bi = (wg & 7) * 32 + (wg >> 3);   // T1: bijective (256 % 8 == 0)
  const int bm = bi >> 3;
  const int bn = bi & 7;
  const int row0 = bm << 7, col0 = bn << 7;
  const int wr = (wave >> 1) << 5;   // 0,32,64,96
  const int wc = (wave & 1) << 6;    // 0,64

  f32x4 acc[2][4];
#pragma unroll
  for (int m = 0; m < 2; ++m)
#pragma unroll
    for (int n = 0; n < 4; ++n) acc[m][n] = (f32x4)0.0f;

  for (int k0 = 0; k0 < 1024; k0 += 64) {
    __syncthreads();
#pragma unroll
    for (int c = 0; c < 2; ++c) {
      const int x = c * 8192 + tid * 16;
      const int gx = x ^ (((x >> 7) & 7) << 4);
      const int row = gx >> 7;
      const int cb = gx & 127;
      const u16* ga = A + (size_t)(row0 + row) * 1024 + k0 + (cb >> 1);
      const u16* gb = BT + (size_t)(col0 + row) * 1024 + k0 + (cb >> 1);
      async16(ga, (char*)Al + x);
      async16(gb, (char*)Bl + x);
    }
    __syncthreads();

    bf16x8 af[2][2], bfr[4][2];
#pragma unroll
    for (int m = 0; m < 2; ++m)
#pragma unroll
      for (int kf = 0; kf < 2; ++kf) {
        int r = wr + m * 16 + l15;
        int byte = ((r << 7) + kf * 64 + lq * 16) ^ ((r & 7) << 4);
        af[m][kf] = *(const bf16x8*)((const char*)Al + byte);
      }
#pragma unroll
    for (int n = 0; n < 4; ++n)
#pragma unroll
      for (int kf = 0; kf < 2; ++kf) {
        int r = wc + n * 16 + l15;
        int byte = ((r << 7) + kf * 64 + lq * 16) ^ ((r & 7) << 4);
        bfr[n][kf] = *(const bf16x8*)((const char*)Bl + byte);
      }
#pragma unroll
    for (int kf = 0; kf < 2; ++kf)
#pragma unroll
      for (int m = 0; m < 2; ++m)
#pragma unroll
        for (int n = 0; n < 4; ++n)
          acc[m][n] = mfma16(bfr[n][kf], af[m][kf], acc[m][n]);
  }

  float4 b4[4];
#pragma unroll
  for (int n = 0; n < 4; ++n)
    b4[n] = *(const float4*)(bias + col0 + wc + n * 16 + lq * 4);
#pragma unroll
  for (int m = 0; m < 2; ++m) {
    int row = row0 + wr + m * 16 + l15;
#pragma unroll
    for (int n = 0; n < 4; ++n) {
      int colbase = col0 + wc + n * 16 + lq * 4;
      float4 v;
      v.x = acc[m][n][0] + b4[n].x;
      v.y = acc[m][n][1] + b4[n].y;
      v.z = acc[m][n][2] + b4[n].z;
      v.w = acc[m][n][3] + b4[n].w;
      *(float4*)(out + (size_t)row * 1024 + colbase) = v;
    }
  }
}

// ---------------- flash attention v3b + setprio (T5) + T1 swizzle ----------------
__global__ __launch_bounds__(256)
void attn(const u16* __restrict__ Qp, const u16* __restrict__ Kp,
          const u16* __restrict__ VpT, u16* __restrict__ Ow) {
  __shared__ alignas(16) u16 Kl[2][64 * 64];
  __shared__ alignas(16) u16 VTl[2][64 * 64];
  __shared__ alignas(16) u16 Pl[4][16 * 64];
  const int tid = threadIdx.x;
  const int wave = tid >> 6;
  const int lane = tid & 63;
  const int l15 = lane & 15, lq = lane >> 4;
  const int wg = blockIdx.x;
  const int swz = (wg & 7) * 128 + (wg >> 3);  // T1: XCD k owns bh in [8k, 8k+8)
  const int qt = swz & 15;
  const int bh = swz >> 4;
  const int b = bh >> 4, h = bh & 15;
  const size_t bS = (size_t)b * S_SZ;

  const int xs0 = tid * 16, xs1 = 4096 + tid * 16;
  const int r0 = xs0 >> 7, r1 = xs1 >> 7;
  const int c0 = ((xs0 & 127) ^ (((xs0 >> 7) & 7) << 4)) >> 1;
  const int c1 = ((xs1 & 127) ^ (((xs1 >> 7) & 7) << 4)) >> 1;
  const u16* Kb0 = Kp + ((bS + r0) << 10) + h * 64 + c0;
  const u16* Kb1 = Kp + ((bS + r1) << 10) + h * 64 + c1;
  const u16* Vb0 = VpT + (size_t)(h * 64 + r0) * 4096 + bS + c0;
  const u16* Vb1 = VpT + (size_t)(h * 64 + r1) * 4096 + bS + c1;

  bf16x8 aq[2];
  {
    const u16* qptr = Qp + ((bS + qt * 64 + wave * 16 + l15) << 10) + h * 64 + lq * 8;
    aq[0] = *(const bf16x8*)(qptr);
    aq[1] = *(const bf16x8*)(qptr + 32);
  }

  f32x4 o[4];
#pragma unroll
  for (int n = 0; n < 4; ++n) o[n] = (f32x4)0.0f;
  float m_run = -1e30f;   // per-lane: q = l15
  float l_run = 0.f;
  u16* Pw = Pl[wave];

  async16(Kb0, (char*)Kl[0] + xs0);
  async16(Kb1, (char*)Kl[0] + xs1);
  async16(Vb0, (char*)VTl[0] + xs0);
  async16(Vb1, (char*)VTl[0] + xs1);
  __syncthreads();

  int buf = 0;
  for (int t0 = 0; t0 < S_SZ; t0 += 64) {
    if (t0 + 64 < S_SZ) {
      const int tn = t0 + 64;
      async16(Kb0 + ((size_t)tn << 10), (char*)Kl[buf ^ 1] + xs0);
      async16(Kb1 + ((size_t)tn << 10), (char*)Kl[buf ^ 1] + xs1);
      async16(Vb0 + tn, (char*)VTl[buf ^ 1] + xs0);
      async16(Vb1 + tn, (char*)VTl[buf ^ 1] + xs1);
    }

    // swapped QK^T: s[n][j] = score[t = n*16+lq*4+j][q = l15]
    f32x4 s[4];
#pragma unroll
    for (int n = 0; n < 4; ++n) s[n] = (f32x4)0.0f;
    __builtin_amdgcn_s_setprio(1);
#pragma unroll
    for (int n = 0; n < 4; ++n)
#pragma unroll
      for (int kf = 0; kf < 2; ++kf) {
        int r = n * 16 + l15;
        int byte = ((r << 7) + kf * 64 + lq * 16) ^ ((r & 7) << 4);
        bf16x8 bk = *(const bf16x8*)((const char*)Kl[buf] + byte);
        s[n] = mfma16(bk, aq[kf], s[n]);
      }
    __builtin_amdgcn_s_setprio(0);

    float mx = s[0][0];
#pragma unroll
    for (int n = 0; n < 4; ++n)
#pragma unroll
      for (int j = 0; j < 4; ++j) mx = fmaxf(mx, s[n][j]);
    mx = fmaxf(mx, __shfl_xor(mx, 16, 64));
    mx = fmaxf(mx, __shfl_xor(mx, 32, 64));

    if (__any(mx > m_run + 8.0f)) {
      float mn = fmaxf(m_run, mx);
      float alpha = __expf(m_run - mn);
      m_run = mn;
      l_run *= alpha;
      float a0 = __shfl(alpha, lq * 4 + 0, 64);
      float a1 = __shfl(alpha, lq * 4 + 1, 64);
      float a2 = __shfl(alpha, lq * 4 + 2, 64);
      float a3 = __shfl(alpha, lq * 4 + 3, 64);
#pragma unroll
      for (int n = 0; n < 4; ++n) {
        o[n][0] *= a0; o[n][1] *= a1; o[n][2] *= a2; o[n][3] *= a3;
      }
    }

    float rs = 0.f;
#pragma unroll
    for (int n = 0; n < 4; ++n) {
      float p0 = __expf(s[n][0] - m_run);
      float p1 = __expf(s[n][1] - m_run);
      float p2 = __expf(s[n][2] - m_run);
      float p3 = __expf(s[n][3] - m_run);
      rs += (p0 + p1) + (p2 + p3);
      u32 lo = pack_bf16(p0, p1);
      u32 hi = pack_bf16(p2, p3);
      int byte = (l15 << 7) + (((n * 32 + lq * 8)) ^ ((l15 & 7) << 4));
      uint2 wv; wv.x = lo; wv.y = hi;
      *(uint2*)((char*)Pw + byte) = wv;
    }
    rs += __shfl_xor(rs, 16, 64);
    rs += __shfl_xor(rs, 32, 64);
    l_run += rs;

    // PV: A = P (row=q=l15, k=t), B = V^T rows (e) from LDS
    __builtin_amdgcn_s_setprio(1);
#pragma unroll
    for (int kf = 0; kf < 2; ++kf) {
      int pbyte = (l15 << 7) + ((kf * 64 + lq * 16) ^ ((l15 & 7) << 4));
      bf16x8 pa = *(const bf16x8*)((const char*)Pw + pbyte);
#pragma unroll
      for (int n = 0; n < 4; ++n) {
        int vr = n * 16 + l15;
        int byte = ((vr << 7) + kf * 64 + lq * 16) ^ ((vr & 7) << 4);
        bf16x8 bv = *(const bf16x8*)((const char*)VTl[buf] + byte);
        o[n] = mfma16(pa, bv, o[n]);
      }
    }
    __builtin_amdgcn_s_setprio(0);

    __syncthreads();
    buf ^= 1;
  }

  float li0 = __shfl(l_run, lq * 4 + 0, 64);
  float li1 = __shfl(l_run, lq * 4 + 1, 64);
  float li2 = __shfl(l_run, lq * 4 + 2, 64);
  float li3 = __shfl(l_run, lq * 4 + 3, 64);
  float inv0 = 1.0f / li0, inv1 = 1.0f / li1, inv2 = 1.0f / li2, inv3 = 1.0f / li3;
#pragma unroll
  for (int n = 0; n < 4; ++n) {
    float vals[4] = {o[n][0] * inv0, o[n][1] * inv1, o[n][2] * inv2, o[n][3] * inv3};
#pragma unroll
    for (int j = 0; j < 4; ++j) {
      int row = qt * 64 + wave * 16 + lq * 4 + j;
      int col = h * 64 + n * 16 + l15;
      Ow[((bS + row) << 10) + col] = f2bf(vals[j]);
    }
  }
}

extern "C" void kernel_launch(void* const* d_in, const int* in_sizes, int n_in,
                              void* d_out, int out_size, void* d_ws, size_t ws_size,
                              hipStream_t stream) {
  const float* q  = (const float*)d_in[0];
  const float* k  = (const float*)d_in[1];
  const float* v  = (const float*)d_in[2];
  const float* Wq = (const float*)d_in[3];
  const float* bq = (const float*)d_in[4];
  const float* Wk = (const float*)d_in[5];
  const float* bk = (const float*)d_in[6];
  const float* Wv = (const float*)d_in[7];
  const float* bv = (const float*)d_in[8];
  const float* Wo = (const float*)d_in[9];
  const float* bo = (const float*)d_in[10];

  char* w = (char*)d_ws;
  const size_t MB = 1u << 20;
  u16* qb  = (u16*)(w + 0 * MB);
  u16* kb  = (u16*)(w + 8 * MB);
  u16* vb  = (u16*)(w + 16 * MB);
  u16* WqT = (u16*)(w + 24 * MB);
  u16* WkT = (u16*)(w + 26 * MB);
  u16* WvT = (u16*)(w + 28 * MB);
  u16* Wob = (u16*)(w + 30 * MB);
  u16* Qp  = (u16*)(w + 32 * MB);
  u16* Kp  = (u16*)(w + 40 * MB);
  u16* VpT = (u16*)(w + 48 * MB);
  u16* wvb = (u16*)(w + 56 * MB);

  cast4<<<6656, 256, 0, stream>>>(q, k, v, Wo, qb, kb, vb, Wob);
  transW3<<<768, 256, 0, stream>>>(Wq, Wk, Wv, WqT, WkT, WvT);

  gemm3<<<768, 256, 0, stream>>>(qb, kb, vb, WqT, WkT, WvT, bq, bk, bv, Qp, Kp, VpT);

  attn<<<B_SZ * H_SZ * (S_SZ / 64), 256, 0, stream>>>(Qp, Kp, VpT, wvb);

  gemmO8<<<256, 512, 0, stream>>>(wvb, Wob, bo, (float*)d_out);
}